// Round 12
// baseline (295.184 us; speedup 1.0000x reference)
//
#include <hip/hip_runtime.h>
#include <hip/hip_bf16.h>

typedef __attribute__((ext_vector_type(8))) short bf16x8;
typedef __attribute__((ext_vector_type(4))) float f32x4;
typedef __attribute__((ext_vector_type(4))) short s16x4;

__device__ __forceinline__ short f2bf(float f) {
  union { float f; unsigned u; } v; v.f = f;
  unsigned r = v.u + 0x7fffu + ((v.u >> 16) & 1u);
  return (short)(r >> 16);
}

__device__ __forceinline__ float bf2f(short s) {
  union { float f; unsigned u; } v; v.u = ((unsigned)(unsigned short)s) << 16;
  return v.f;
}

#define GLD_LDS(g, l) __builtin_amdgcn_global_load_lds( \
    (const __attribute__((address_space(1))) void*)(g), \
    (__attribute__((address_space(3))) void*)(l), 16, 0, 0)

// ---- x -> xb + xbT (tiled transpose) + fused per-batch column sums (atomic) ----
__global__ __launch_bounds__(256)
void convt_k(const float* __restrict__ x, short* __restrict__ xb,
             short* __restrict__ xbT, float* __restrict__ s) {
  __shared__ short tile[64][72];
  __shared__ float red[4][64];
  const int b = blockIdx.z;
  const int n0 = blockIdx.y * 64;
  const int c0 = blockIdx.x * 64;
  const int t = threadIdx.x;
  const int nl = t >> 4;
  const int c4 = (t & 15) << 2;
  const float* xp = x + ((size_t)b * 4096 + n0) * 1024 + c0;
#pragma unroll
  for (int i = 0; i < 4; ++i) {
    const int n = nl + 16 * i;
    const float4 v = *(const float4*)(xp + (size_t)n * 1024 + c4);
    s16x4 o;
    o[0] = f2bf(v.x); o[1] = f2bf(v.y); o[2] = f2bf(v.z); o[3] = f2bf(v.w);
    *(s16x4*)(&xb[((size_t)b * 4096 + n0 + n) * 1024 + c0 + c4]) = o;
    *(s16x4*)(&tile[n][c4]) = o;
  }
  __syncthreads();
  const int cll = t >> 4;
  const int n4 = (t & 15) << 2;
#pragma unroll
  for (int i = 0; i < 4; ++i) {
    const int c = cll + 16 * i;
    s16x4 o;
    o[0] = tile[n4 + 0][c]; o[1] = tile[n4 + 1][c];
    o[2] = tile[n4 + 2][c]; o[3] = tile[n4 + 3][c];
    *(s16x4*)(&xbT[((size_t)b * 1024 + c0 + c) * 4096 + n0 + n4]) = o;
  }
  const int part = t >> 6, col = t & 63;
  float cs = 0.f;
#pragma unroll
  for (int i = 0; i < 16; ++i) cs += bf2f(tile[part * 16 + i][col]);
  red[part][col] = cs;
  __syncthreads();
  if (part == 0)
    atomicAdd(&s[b * 1024 + c0 + col],
              red[0][col] + red[1][col] + red[2][col] + red[3][col]);
}

// ------- weights: Wt[d][c] = W[c][d] (+I for z<5; g-fold z==5); wqn = I+Wq row-major -------
__global__ void twc_k(const float* __restrict__ Wq, const float* __restrict__ Wk,
                      const float* __restrict__ Wv, const float* __restrict__ Wo,
                      const float* __restrict__ lng, short* __restrict__ dst,
                      short* __restrict__ wqn) {
  __shared__ float tile[32][33];
  const int z = blockIdx.z;
  const float* src = (z == 0) ? Wq
                   : (z == 1) ? Wk
                   : (z == 2) ? (Wk + 1048576)
                   : (z == 3) ? Wv
                   : (z == 4) ? (Wv + 1048576)
                   : Wo;
  short* d = dst + (size_t)z * 1048576;
  const int tx = threadIdx.x, ty = threadIdx.y;
  const int c0 = blockIdx.y * 32, d0 = blockIdx.x * 32;
#pragma unroll
  for (int i = 0; i < 4; ++i) {
    const int cc = c0 + ty + i * 8;
    const float v = src[(size_t)cc * 1024 + d0 + tx];
    tile[ty + i * 8][tx] = v;
    if (z == 0)
      wqn[(size_t)cc * 1024 + d0 + tx] = f2bf(v + (cc == d0 + tx ? 1.0f : 0.0f));
  }
  __syncthreads();
#pragma unroll
  for (int i = 0; i < 4; ++i) {
    const int cc = c0 + tx;
    const int dd = d0 + ty + i * 8;
    float v = tile[tx][ty + i * 8];
    if (z < 5) {
      if (cc == dd) v += 1.0f;
    } else {
      v *= lng[cc];
    }
    d[(size_t)dd * 1024 + cc] = f2bf(v);
  }
}

// ------- u[k][b] = W~k^T s_b ; w[k][b] = W~v^T s_b -------
__global__ __launch_bounds__(256)
void gemv_k(const short* __restrict__ wt, const float* __restrict__ s,
            float* __restrict__ u, float* __restrict__ w) {
  const int z = blockIdx.z, b = blockIdx.y;
  const int lane = threadIdx.x & 63, wid = threadIdx.x >> 6;
  const short* W = wt + ((size_t)(z + 1) << 20);
  const float* sb = s + b * 1024;
  float* outp = (z < 2) ? (u + (z * 4 + b) * 1024) : (w + ((z - 2) * 4 + b) * 1024);
#pragma unroll 1
  for (int it = 0; it < 16; ++it) {
    const int d = blockIdx.x * 64 + wid * 16 + it;
    const short* row = W + (size_t)d * 1024 + lane * 16;
    float acc = 0.f;
#pragma unroll
    for (int j = 0; j < 16; ++j) acc += bf2f(row[j]) * sb[lane * 16 + j];
#pragma unroll
    for (int o = 32; o > 0; o >>= 1) acc += __shfl_down(acc, o);
    if (lane == 0) outp[d] = acc;
  }
}

// ------- u[d] = sum_c g[c]Wo[c,d];  t[d] = sum_c b[c]Wo[c,d] + bo[d] -------
__global__ __launch_bounds__(256)
void ut_k(const float* __restrict__ Wo, const float* __restrict__ lng,
          const float* __restrict__ lnb, const float* __restrict__ bo,
          float* __restrict__ u, float* __restrict__ t) {
  const int dl = threadIdx.x & 63;
  const int dd = blockIdx.x * 64 + dl;
  const int part = threadIdx.x >> 6;
  float su = 0.f, st = 0.f;
  for (int c = part * 256; c < part * 256 + 256; ++c) {
    const float w = Wo[(size_t)c * 1024 + dd];
    su += lng[c] * w;
    st += lnb[c] * w;
  }
  __shared__ float rs[4][64], rt[4][64];
  rs[part][dl] = su; rt[part][dl] = st;
  __syncthreads();
  if (part == 0) {
    su = rs[0][dl] + rs[1][dl] + rs[2][dl] + rs[3][dl];
    st = rt[0][dl] + rt[1][dl] + rt[2][dl] + rt[3][dl];
    u[dd] = su;
    t[dd] = st + bo[dd];
  }
}

// ======== unified 128x128-tile BK=32 3-buffer counted-vmcnt GEMM ========
// NOTE: no min-occupancy bound — R11's (256,3) forced 64 VGPRs and spilled the
// 64-VGPR accumulator to scratch (VGPR_Count=64 in counters, 2.5x slowdown).
// MODE 0: gram upper-triangle  Pg[kz][b](ti,tj) = xbT_b rows x rows^T      (fp32)
// MODE 1: stage1  Tt[b] = wt_v(2048x1024) @ Gt[b]                         (bf16)
// MODE 2: oat = xb @ Beff[b]^T + rq -> bf16 + LN-stat atomics
// MODE 3: gemmo = oat @ Wg^T with folded-LN epilogue                      (fp32)
template <int MODE>
__global__ __launch_bounds__(256)
void g128_k(const short* __restrict__ A0, const short* __restrict__ B0,
            const float* __restrict__ cr0, const float* __restrict__ cr1,
            float* __restrict__ musum, float* __restrict__ sqsum,
            short* __restrict__ obf, float* __restrict__ of32) {
  extern __shared__ short lds[];  // 49152 B = 3 bufs x (4096 A + 4096 B shorts)
  const int tid = threadIdx.x, lane = tid & 63, wid = tid >> 6;
  const int wm = (wid >> 1) << 6, wn = (wid & 1) << 6;
  const int lrow = ((lane >> 3) << 1) | ((lane >> 2) & 1);
  const int kc = ((lane & 3) ^ ((lane >> 3) & 3)) << 3;
  const int cl = lane & 15, khi = lane >> 4;

  int bm0, bn0, koff = 0, b = 0, ld;
  const short *Ap, *Bp;
  if constexpr (MODE == 0) {
    const int swz = (blockIdx.x & 7) * 72 + (blockIdx.x >> 3);  // 576, XCD-bijective
    const int panel = swz / 36;   // b*4+kz : 36-tile panels stay on one XCD
    int uu2 = swz % 36;
    b = panel >> 2;
    const int kz = panel & 3;
    int ti = 0;
    while (uu2 >= 8 - ti) { uu2 -= 8 - ti; ++ti; }
    const int tj = ti + uu2;
    bm0 = ti << 7; bn0 = tj << 7;
    koff = kz << 10; ld = 4096;
    Ap = A0 + ((size_t)b << 22);
    Bp = Ap;
    of32 += ((size_t)((kz << 2) + b) << 20);
  } else if constexpr (MODE == 1) {
    const int swz = (blockIdx.x & 7) * 64 + (blockIdx.x >> 3);  // 512
    b = swz >> 7;
    const int tl = swz & 127;
    bm0 = (tl >> 3) << 7; bn0 = (tl & 7) << 7;
    ld = 1024;
    Ap = A0;
    Bp = B0 + ((size_t)b << 20);
    obf += ((size_t)b << 21);
  } else if constexpr (MODE == 2) {
    const int swz = (blockIdx.x & 7) * 128 + (blockIdx.x >> 3); // 1024
    b = swz >> 8;
    const int tl = swz & 255;
    bm0 = (tl >> 3) << 7; bn0 = (tl & 7) << 7;
    ld = 1024;
    Ap = A0 + ((size_t)b << 22);
    Bp = B0 + ((size_t)b << 20);
  } else {
    const int swz = (blockIdx.x & 7) * 128 + (blockIdx.x >> 3); // 1024
    bm0 = (swz >> 3) << 7; bn0 = (swz & 7) << 7;
    ld = 1024;
    Ap = A0; Bp = B0;
  }

  f32x4 acc[4][4];
#pragma unroll
  for (int i = 0; i < 4; ++i)
#pragma unroll
    for (int j = 0; j < 4; ++j) acc[i][j] = f32x4{0.f, 0.f, 0.f, 0.f};

  auto stage = [&](int buf, int t) {
    const int k0 = koff + (t << 5) + kc;
    short* ab = lds + buf * 8192;
    short* bb = ab + 4096;
#pragma unroll
    for (int c = 0; c < 2; ++c) {
      const int un = wid * 2 + c;
      GLD_LDS(Ap + (size_t)(bm0 + (un << 4) + lrow) * ld + k0, ab + (un << 9));
      GLD_LDS(Bp + (size_t)(bn0 + (un << 4) + lrow) * ld + k0, bb + (un << 9));
    }
  };

  auto compute = [&](int buf) {
    const short* ab = lds + buf * 8192;
    const short* bb = ab + 4096;
    bf16x8 af[4], bfr[4];
#pragma unroll
    for (int i = 0; i < 4; ++i) {
      const int R = wm + (i << 4) + cl;
      af[i] = *(const bf16x8*)(ab + (R << 5) + ((khi ^ ((R >> 1) & 3)) << 3));
    }
#pragma unroll
    for (int j = 0; j < 4; ++j) {
      const int C = wn + (j << 4) + cl;
      bfr[j] = *(const bf16x8*)(bb + (C << 5) + ((khi ^ ((C >> 1) & 3)) << 3));
    }
#pragma unroll
    for (int i = 0; i < 4; ++i)
#pragma unroll
      for (int j = 0; j < 4; ++j)
        acc[i][j] = __builtin_amdgcn_mfma_f32_16x16x32_bf16(af[i], bfr[j], acc[i][j], 0, 0, 0);
  };

  // 3-buffer pipeline over 32 K-tiles; vmcnt(4) never drains in steady state.
  stage(0, 0);
  stage(1, 1);
  asm volatile("s_waitcnt vmcnt(4)" ::: "memory");
  __builtin_amdgcn_s_barrier();
#pragma unroll 1
  for (int t = 0; t < 30; ++t) {
    stage((t + 2) % 3, t + 2);
    compute(t % 3);
    asm volatile("s_waitcnt vmcnt(4)" ::: "memory");
    __builtin_amdgcn_s_barrier();
  }
  compute(0);  // tile 30 (buf 30%3=0)
  asm volatile("s_waitcnt vmcnt(0)" ::: "memory");
  __builtin_amdgcn_s_barrier();
  compute(1);  // tile 31 (buf 31%3=1)

  if constexpr (MODE == 0) {
#pragma unroll
    for (int i = 0; i < 4; ++i)
#pragma unroll
      for (int j = 0; j < 4; ++j) {
        const int col = bn0 + wn + (j << 4) + cl;
        const int rowb = bm0 + wm + (i << 4) + (khi << 2);
#pragma unroll
        for (int r = 0; r < 4; ++r)
          of32[(size_t)(rowb + r) * 1024 + col] = acc[i][j][r];
      }
  } else if constexpr (MODE == 1) {
#pragma unroll
    for (int i = 0; i < 4; ++i)
#pragma unroll
      for (int j = 0; j < 4; ++j) {
        const int col = bn0 + wn + (j << 4) + cl;
        const int rowb = bm0 + wm + (i << 4) + (khi << 2);
#pragma unroll
        for (int r = 0; r < 4; ++r)
          obf[(size_t)(rowb + r) * 1024 + col] = f2bf(acc[i][j][r]);
      }
  } else if constexpr (MODE == 2) {
#pragma unroll
    for (int i = 0; i < 4; ++i) {
      const int rowb = bm0 + wm + (i << 4) + (khi << 2);
      s16x4 pk[4];
#pragma unroll
      for (int j = 0; j < 4; ++j) {
        const int col = bn0 + wn + (j << 4) + cl;
        const float rqc = cr0[b * 1024 + col];
#pragma unroll
        for (int r = 0; r < 4; ++r) pk[j][r] = f2bf(acc[i][j][r] + rqc);
#pragma unroll
        for (int r = 0; r < 4; ++r)
          obf[(size_t)(b * 4096 + rowb + r) * 1024 + col] = pk[j][r];
      }
#pragma unroll
      for (int r = 0; r < 4; ++r) {
        float sv = 0.f, sq = 0.f;
#pragma unroll
        for (int j = 0; j < 4; ++j) {
          const float fv = bf2f(pk[j][r]);
          sv += fv; sq += fv * fv;
        }
#pragma unroll
        for (int m = 1; m < 16; m <<= 1) {
          sv += __shfl_xor(sv, m);
          sq += __shfl_xor(sq, m);
        }
        if (cl == 0) {
          atomicAdd(&musum[b * 4096 + rowb + r], sv);
          atomicAdd(&sqsum[b * 4096 + rowb + r], sq);
        }
      }
    }
  } else {
#pragma unroll
    for (int i = 0; i < 4; ++i) {
      const int rowb = bm0 + wm + (i << 4) + (khi << 2);
      const float4 ms = *(const float4*)(musum + rowb);
      const float4 qs = *(const float4*)(sqsum + rowb);
      float mu[4], rs[4];
      mu[0] = ms.x * (1.0f / 1024.0f); mu[1] = ms.y * (1.0f / 1024.0f);
      mu[2] = ms.z * (1.0f / 1024.0f); mu[3] = ms.w * (1.0f / 1024.0f);
      rs[0] = rsqrtf(fmaxf(qs.x * (1.0f / 1024.0f) - mu[0] * mu[0], 0.f) + 1e-5f);
      rs[1] = rsqrtf(fmaxf(qs.y * (1.0f / 1024.0f) - mu[1] * mu[1], 0.f) + 1e-5f);
      rs[2] = rsqrtf(fmaxf(qs.z * (1.0f / 1024.0f) - mu[2] * mu[2], 0.f) + 1e-5f);
      rs[3] = rsqrtf(fmaxf(qs.w * (1.0f / 1024.0f) - mu[3] * mu[3], 0.f) + 1e-5f);
#pragma unroll
      for (int j = 0; j < 4; ++j) {
        const int col = bn0 + wn + (j << 4) + cl;
        const float uc = cr0[col];
        const float tc = cr1[col];
#pragma unroll
        for (int r = 0; r < 4; ++r)
          of32[(size_t)(rowb + r) * 1024 + col] = rs[r] * (acc[i][j][r] - mu[r] * uc) + tc;
      }
    }
  }
}

// ------- reduce upper 64-tiles of Pg, write Gt tile + mirrored transpose -------
__global__ __launch_bounds__(256)
void gred_k(const float* __restrict__ Pg, short* __restrict__ G) {
  __shared__ short tile[64][72];
  const int bid = blockIdx.x;  // 544 = 4b x 136 upper 64-tiles
  const int b = bid / 136;
  int u = bid % 136;
  int ti = 0;
  while (u >= 16 - ti) { u -= 16 - ti; ++ti; }
  const int tj = ti + u;
  const int r = threadIdx.x >> 2;
  const int c0 = (threadIdx.x & 3) << 4;
  float acc[16];
#pragma unroll
  for (int q = 0; q < 16; ++q) acc[q] = 0.f;
#pragma unroll
  for (int kz = 0; kz < 4; ++kz) {
    const float* p = Pg + (((size_t)((kz << 2) + b)) << 20)
                   + (size_t)(ti * 64 + r) * 1024 + tj * 64 + c0;
#pragma unroll
    for (int q4 = 0; q4 < 4; ++q4) {
      const float4 v = ((const float4*)p)[q4];
      acc[q4 * 4 + 0] += v.x; acc[q4 * 4 + 1] += v.y;
      acc[q4 * 4 + 2] += v.z; acc[q4 * 4 + 3] += v.w;
    }
  }
  const float sc = 1.0f / 4096.0f;
  short* gb = G + ((size_t)b << 20);
#pragma unroll
  for (int q4 = 0; q4 < 4; ++q4) {
    s16x4 o;
#pragma unroll
    for (int e = 0; e < 4; ++e) {
      o[e] = f2bf(acc[q4 * 4 + e] * sc);
      tile[r][c0 + q4 * 4 + e] = o[e];
    }
    *(s16x4*)(gb + (size_t)(ti * 64 + r) * 1024 + tj * 64 + c0 + q4 * 4) = o;
  }
  __syncthreads();
  if (ti != tj) {
#pragma unroll
    for (int q4 = 0; q4 < 4; ++q4) {
      s16x4 o;
#pragma unroll
      for (int e = 0; e < 4; ++e) o[e] = tile[c0 + q4 * 4 + e][r];
      *(s16x4*)(gb + (size_t)(tj * 64 + r) * 1024 + ti * 64 + c0 + q4 * 4) = o;
    }
  }
}

// ------- fused stage-2 + combine + weff: one block per (b,h) -------
__global__ __launch_bounds__(256)
void sw_k(const short* __restrict__ wt, const short* __restrict__ Tt,
          const float* __restrict__ u, const float* __restrict__ w,
          const float* __restrict__ bk, const float* __restrict__ bv,
          const short* __restrict__ wqn, const float* __restrict__ bq,
          short* __restrict__ Beff, float* __restrict__ rq) {
  __shared__ short Al[64 * 40];
  __shared__ short Bl[64 * 40];
  __shared__ short S[64][72];
  const int h = blockIdx.x & 15, b = blockIdx.x >> 4;
  const int tid = threadIdx.x, lane = tid & 63, wid = tid >> 6;
  const int srow = tid >> 2, sch = (tid & 3) << 3;
  const int cl = lane & 15, khi = lane >> 4;

  f32x4 acc2[2][4];
#pragma unroll
  for (int k = 0; k < 2; ++k)
#pragma unroll
    for (int j = 0; j < 4; ++j) acc2[k][j] = f32x4{0.f, 0.f, 0.f, 0.f};

#pragma unroll
  for (int k = 0; k < 2; ++k) {
    const short* Ap = wt + ((size_t)(1 + k) << 20) + ((size_t)(h * 64) << 10);
    const short* Bp = Tt + ((size_t)b << 21) + ((size_t)(k * 1024 + h * 64) << 10);
#pragma unroll 1
    for (int ns = 0; ns < 1024; ns += 32) {
      bf16x8 va = *(const bf16x8*)(Ap + ((size_t)srow << 10) + ns + sch);
      bf16x8 vb = *(const bf16x8*)(Bp + ((size_t)srow << 10) + ns + sch);
      __syncthreads();
      *(bf16x8*)(Al + srow * 40 + sch) = va;
      *(bf16x8*)(Bl + srow * 40 + sch) = vb;
      __syncthreads();
      bf16x8 a = *(const bf16x8*)(Al + (wid * 16 + cl) * 40 + (khi << 3));
#pragma unroll
      for (int j = 0; j < 4; ++j) {
        bf16x8 bb = *(const bf16x8*)(Bl + (j * 16 + cl) * 40 + (khi << 3));
        acc2[k][j] = __builtin_amdgcn_mfma_f32_16x16x32_bf16(a, bb, acc2[k][j], 0, 0, 0);
      }
    }
  }

  const int d0 = wid * 16 + (khi << 2);
  const float invN = 1.0f / 4096.0f;
#pragma unroll
  for (int j = 0; j < 4; ++j) {
    const int e = j * 16 + cl;
    s16x4 pk;
#pragma unroll
    for (int r = 0; r < 4; ++r) {
      const int d = d0 + r;
      float m[2];
#pragma unroll
      for (int k = 0; k < 2; ++k) {
        const float bkd = bk[k * 1024 + h * 64 + d];
        const float bve = bv[k * 1024 + h * 64 + e];
        const float ud = u[(k * 4 + b) * 1024 + h * 64 + d];
        const float we = w[(k * 4 + b) * 1024 + h * 64 + e];
        m[k] = acc2[k][j][r] + (ud * bve + bkd * we + 4096.f * bkd * bve) * invN;
      }
      pk[r] = f2bf(m[0] * m[1]);
    }
    *(s16x4*)(&S[e][d0]) = pk;
  }
  __syncthreads();

  if (wid == 0) {
    float acc = 0.f;
#pragma unroll 1
    for (int d = 0; d < 64; ++d) acc += bq[h * 64 + d] * bf2f(S[lane][d]);
    rq[b * 1024 + h * 64 + lane] = acc;
  }
  bf16x8 af[4][2];
#pragma unroll
  for (int mi = 0; mi < 4; ++mi)
#pragma unroll
    for (int kk = 0; kk < 2; ++kk)
      af[mi][kk] = *(const bf16x8*)(&S[mi * 16 + cl][kk * 32 + khi * 8]);
  const short* wq = wqn + h * 64;
  short* bdst = Beff + ((size_t)b << 20) + ((size_t)(h * 64) << 10);
#pragma unroll 1
  for (int nf = 0; nf < 16; ++nf) {
    const int c0 = wid * 256 + nf * 16;
    const bf16x8 bf0 = *(const bf16x8*)(wq + (size_t)(c0 + cl) * 1024 + khi * 8);
    const bf16x8 bf1 = *(const bf16x8*)(wq + (size_t)(c0 + cl) * 1024 + 32 + khi * 8);
    f32x4 a4[4];
#pragma unroll
    for (int mi = 0; mi < 4; ++mi) {
      a4[mi] = f32x4{0.f, 0.f, 0.f, 0.f};
      a4[mi] = __builtin_amdgcn_mfma_f32_16x16x32_bf16(af[mi][0], bf0, a4[mi], 0, 0, 0);
      a4[mi] = __builtin_amdgcn_mfma_f32_16x16x32_bf16(af[mi][1], bf1, a4[mi], 0, 0, 0);
    }
#pragma unroll
    for (int mi = 0; mi < 4; ++mi)
#pragma unroll
      for (int r = 0; r < 4; ++r)
        bdst[(size_t)(mi * 16 + khi * 4 + r) * 1024 + c0 + cl] = f2bf(a4[mi][r]);
  }
}

extern "C" void kernel_launch(void* const* d_in, const int* in_sizes, int n_in,
                              void* d_out, int out_size, void* d_ws, size_t ws_size,
                              hipStream_t stream) {
  const float* x = (const float*)d_in[0];
  const float* Wq = (const float*)d_in[1];
  const float* bq = (const float*)d_in[2];
  const float* Wk = (const float*)d_in[3];
  const float* bk = (const float*)d_in[4];
  const float* Wv = (const float*)d_in[5];
  const float* bv = (const float*)d_in[6];
  const float* Wo = (const float*)d_in[7];
  const float* bo = (const float*)d_in[8];
  const float* lng = (const float*)d_in[9];
  const float* lnb = (const float*)d_in[10];

  char* ws = (char*)d_ws;
  short* xb = (short*)(ws + 0);             // [0, 33554432)
  short* wt = (short*)(ws + 33554432);      // [33554432, 46137344)
  short* wqn = (short*)(ws + 46137344);     // [46137344, 48234496)
  short* Beff = (short*)(ws + 48234496);    // [48234496, 56623104)
  float* rq = (float*)(ws + 56623104);      // [56623104, 56639488)
  float* musum = (float*)(ws + 56639488);   // [56639488, 56705024)
  float* sqsum = (float*)(ws + 56705024);   // [56705024, 56770560)
  float* s = (float*)(ws + 56770560);       // [56770560, 56786944)  zeroed w/ musum
  float* u = (float*)(ws + 56786944);       // [56786944, 56819712)
  float* w = (float*)(ws + 56819712);       // [56819712, 56852480)
  float* uu = (float*)(ws + 56852480);      // [56852480, 56856576)
  float* tt = (float*)(ws + 56856576);      // [56856576, 56860672)
  short* xbT = (short*)(ws + 79691776);     // [79691776, 113246208) dead after gram
  short* Gt = (short*)(ws + 113246208);     // [113246208, 121634816)
  short* Tt = (short*)(ws + 121634816);     // [121634816, 138412032)
  float* Pg = (float*)(ws + 143351808);     // [143351808, 210460672)
  short* oat = xbT;

  hipMemsetAsync(musum, 0, 147456, stream);
  convt_k<<<dim3(16, 64, 4), 256, 0, stream>>>(x, xb, xbT, s);
  twc_k<<<dim3(32, 32, 6), dim3(32, 8), 0, stream>>>(Wq, Wk, Wv, Wo, lng, wt, wqn);
  gemv_k<<<dim3(16, 4, 4), 256, 0, stream>>>(wt, s, u, w);
  ut_k<<<16, 256, 0, stream>>>(Wo, lng, lnb, bo, uu, tt);

  // gram: upper-triangle 128-tiles only (G symmetric)
  g128_k<0><<<576, 256, 49152, stream>>>(xbT, nullptr, nullptr, nullptr,
                                         nullptr, nullptr, nullptr, Pg);
  gred_k<<<544, 256, 0, stream>>>(Pg, Gt);
  g128_k<1><<<512, 256, 49152, stream>>>(wt + 3145728, Gt, nullptr, nullptr,
                                         nullptr, nullptr, Tt, nullptr);
  sw_k<<<64, 256, 0, stream>>>(wt, Tt, u, w, bk, bv, wqn, bq, Beff, rq);

  g128_k<2><<<1024, 256, 49152, stream>>>(xb, Beff, rq, nullptr,
                                          musum, sqsum, oat, nullptr);
  g128_k<3><<<1024, 256, 49152, stream>>>(oat, wt + 5242880, uu, tt,
                                          musum, sqsum, nullptr, (float*)d_out);
}

// Round 13
// 288.378 us; speedup vs baseline: 1.0236x; 1.0236x over previous
//
#include <hip/hip_runtime.h>
#include <hip/hip_bf16.h>

typedef __attribute__((ext_vector_type(8))) short bf16x8;
typedef __attribute__((ext_vector_type(4))) float f32x4;
typedef __attribute__((ext_vector_type(4))) short s16x4;

__device__ __forceinline__ short f2bf(float f) {
  union { float f; unsigned u; } v; v.f = f;
  unsigned r = v.u + 0x7fffu + ((v.u >> 16) & 1u);
  return (short)(r >> 16);
}

__device__ __forceinline__ float bf2f(short s) {
  union { float f; unsigned u; } v; v.u = ((unsigned)(unsigned short)s) << 16;
  return v.f;
}

#define GLD_LDS(g, l) __builtin_amdgcn_global_load_lds( \
    (const __attribute__((address_space(1))) void*)(g), \
    (__attribute__((address_space(3))) void*)(l), 16, 0, 0)

// ---- x -> xb + xbT (tiled transpose) + fused per-batch column sums (atomic) ----
__global__ __launch_bounds__(256)
void convt_k(const float* __restrict__ x, short* __restrict__ xb,
             short* __restrict__ xbT, float* __restrict__ s) {
  __shared__ short tile[64][72];
  __shared__ float red[4][64];
  const int b = blockIdx.z;
  const int n0 = blockIdx.y * 64;
  const int c0 = blockIdx.x * 64;
  const int t = threadIdx.x;
  const int nl = t >> 4;
  const int c4 = (t & 15) << 2;
  const float* xp = x + ((size_t)b * 4096 + n0) * 1024 + c0;
#pragma unroll
  for (int i = 0; i < 4; ++i) {
    const int n = nl + 16 * i;
    const float4 v = *(const float4*)(xp + (size_t)n * 1024 + c4);
    s16x4 o;
    o[0] = f2bf(v.x); o[1] = f2bf(v.y); o[2] = f2bf(v.z); o[3] = f2bf(v.w);
    *(s16x4*)(&xb[((size_t)b * 4096 + n0 + n) * 1024 + c0 + c4]) = o;
    *(s16x4*)(&tile[n][c4]) = o;
  }
  __syncthreads();
  const int cll = t >> 4;
  const int n4 = (t & 15) << 2;
#pragma unroll
  for (int i = 0; i < 4; ++i) {
    const int c = cll + 16 * i;
    s16x4 o;
    o[0] = tile[n4 + 0][c]; o[1] = tile[n4 + 1][c];
    o[2] = tile[n4 + 2][c]; o[3] = tile[n4 + 3][c];
    *(s16x4*)(&xbT[((size_t)b * 1024 + c0 + c) * 4096 + n0 + n4]) = o;
  }
  const int part = t >> 6, col = t & 63;
  float cs = 0.f;
#pragma unroll
  for (int i = 0; i < 16; ++i) cs += bf2f(tile[part * 16 + i][col]);
  red[part][col] = cs;
  __syncthreads();
  if (part == 0)
    atomicAdd(&s[b * 1024 + c0 + col],
              red[0][col] + red[1][col] + red[2][col] + red[3][col]);
}

// ------- weights: Wt[d][c] = W[c][d] (+I for z<5; g-fold z==5); wqn = I+Wq row-major -------
__global__ void twc_k(const float* __restrict__ Wq, const float* __restrict__ Wk,
                      const float* __restrict__ Wv, const float* __restrict__ Wo,
                      const float* __restrict__ lng, short* __restrict__ dst,
                      short* __restrict__ wqn) {
  __shared__ float tile[32][33];
  const int z = blockIdx.z;
  const float* src = (z == 0) ? Wq
                   : (z == 1) ? Wk
                   : (z == 2) ? (Wk + 1048576)
                   : (z == 3) ? Wv
                   : (z == 4) ? (Wv + 1048576)
                   : Wo;
  short* d = dst + (size_t)z * 1048576;
  const int tx = threadIdx.x, ty = threadIdx.y;
  const int c0 = blockIdx.y * 32, d0 = blockIdx.x * 32;
#pragma unroll
  for (int i = 0; i < 4; ++i) {
    const int cc = c0 + ty + i * 8;
    const float v = src[(size_t)cc * 1024 + d0 + tx];
    tile[ty + i * 8][tx] = v;
    if (z == 0)
      wqn[(size_t)cc * 1024 + d0 + tx] = f2bf(v + (cc == d0 + tx ? 1.0f : 0.0f));
  }
  __syncthreads();
#pragma unroll
  for (int i = 0; i < 4; ++i) {
    const int cc = c0 + tx;
    const int dd = d0 + ty + i * 8;
    float v = tile[tx][ty + i * 8];
    if (z < 5) {
      if (cc == dd) v += 1.0f;
    } else {
      v *= lng[cc];
    }
    d[(size_t)dd * 1024 + cc] = f2bf(v);
  }
}

// ------- u[k][b] = W~k^T s_b ; w[k][b] = W~v^T s_b -------
__global__ __launch_bounds__(256)
void gemv_k(const short* __restrict__ wt, const float* __restrict__ s,
            float* __restrict__ u, float* __restrict__ w) {
  const int z = blockIdx.z, b = blockIdx.y;
  const int lane = threadIdx.x & 63, wid = threadIdx.x >> 6;
  const short* W = wt + ((size_t)(z + 1) << 20);
  const float* sb = s + b * 1024;
  float* outp = (z < 2) ? (u + (z * 4 + b) * 1024) : (w + ((z - 2) * 4 + b) * 1024);
#pragma unroll 1
  for (int it = 0; it < 16; ++it) {
    const int d = blockIdx.x * 64 + wid * 16 + it;
    const short* row = W + (size_t)d * 1024 + lane * 16;
    float acc = 0.f;
#pragma unroll
    for (int j = 0; j < 16; ++j) acc += bf2f(row[j]) * sb[lane * 16 + j];
#pragma unroll
    for (int o = 32; o > 0; o >>= 1) acc += __shfl_down(acc, o);
    if (lane == 0) outp[d] = acc;
  }
}

// ------- u[d] = sum_c g[c]Wo[c,d];  t[d] = sum_c b[c]Wo[c,d] + bo[d] -------
__global__ __launch_bounds__(256)
void ut_k(const float* __restrict__ Wo, const float* __restrict__ lng,
          const float* __restrict__ lnb, const float* __restrict__ bo,
          float* __restrict__ u, float* __restrict__ t) {
  const int dl = threadIdx.x & 63;
  const int dd = blockIdx.x * 64 + dl;
  const int part = threadIdx.x >> 6;
  float su = 0.f, st = 0.f;
  for (int c = part * 256; c < part * 256 + 256; ++c) {
    const float w = Wo[(size_t)c * 1024 + dd];
    su += lng[c] * w;
    st += lnb[c] * w;
  }
  __shared__ float rs[4][64], rt[4][64];
  rs[part][dl] = su; rt[part][dl] = st;
  __syncthreads();
  if (part == 0) {
    su = rs[0][dl] + rs[1][dl] + rs[2][dl] + rs[3][dl];
    st = rt[0][dl] + rt[1][dl] + rt[2][dl] + rt[3][dl];
    u[dd] = su;
    t[dd] = st + bo[dd];
  }
}

// ======== unified 128x128-tile BK=32 4-buffer (&3) counted-vmcnt GEMM ========
// Exact structure of R10's measured-good gemm128_k: 64KB LDS, (256,2), &3 bufs.
// MODE 0: gram full  Pg[kz][b] = xbT_b chunk @ xbT_b chunk^T                (fp32)
// MODE 1: stage1  Tt[b] = wt_v(2048x1024) @ Gt[b]                           (bf16)
// MODE 2: oat = xb @ Beff[b]^T + rq -> bf16 + LN-stat atomics
// MODE 3: gemmo = oat @ Wg^T with folded-LN epilogue                        (fp32)
template <int MODE>
__global__ __launch_bounds__(256, 2)
void g4_k(const short* __restrict__ A0, const short* __restrict__ B0,
          const float* __restrict__ cr0, const float* __restrict__ cr1,
          float* __restrict__ musum, float* __restrict__ sqsum,
          short* __restrict__ obf, float* __restrict__ of32) {
  extern __shared__ short lds[];  // 65536 B = 4 bufs x (4096 A + 4096 B shorts)
  const int tid = threadIdx.x, lane = tid & 63, wid = tid >> 6;
  const int wm = (wid >> 1) << 6, wn = (wid & 1) << 6;
  const int lrow = ((lane >> 3) << 1) | ((lane >> 2) & 1);
  const int kc = ((lane & 3) ^ ((lane >> 3) & 3)) << 3;
  const int cl = lane & 15, khi = lane >> 4;

  int bm0, bn0, koff = 0, b = 0, ld;
  const short *Ap, *Bp;
  if constexpr (MODE == 0) {
    const int swz = (blockIdx.x & 7) * 128 + (blockIdx.x >> 3);  // 1024
    const int panel = swz >> 6;       // b*4+kz: 64-tile panels, 2 per XCD chunk
    b = panel >> 2;
    const int kz = panel & 3;
    const int tl = swz & 63;
    bm0 = (tl >> 3) << 7; bn0 = (tl & 7) << 7;
    koff = kz << 10; ld = 4096;
    Ap = A0 + ((size_t)b << 22);
    Bp = Ap;
    of32 += ((size_t)((kz << 2) + b) << 20);
  } else if constexpr (MODE == 1) {
    const int swz = (blockIdx.x & 7) * 64 + (blockIdx.x >> 3);   // 512
    b = swz >> 7;
    const int tl = swz & 127;
    bm0 = (tl >> 3) << 7; bn0 = (tl & 7) << 7;
    ld = 1024;
    Ap = A0;
    Bp = B0 + ((size_t)b << 20);
    obf += ((size_t)b << 21);
  } else if constexpr (MODE == 2) {
    const int swz = (blockIdx.x & 7) * 128 + (blockIdx.x >> 3);  // 1024
    b = swz >> 8;
    const int tl = swz & 255;
    bm0 = (tl >> 3) << 7; bn0 = (tl & 7) << 7;   // bn-inner: A-slab L2 reuse
    ld = 1024;
    Ap = A0 + ((size_t)b << 22);
    Bp = B0 + ((size_t)b << 20);
  } else {
    const int swz = (blockIdx.x & 7) * 128 + (blockIdx.x >> 3);  // 1024
    bm0 = (swz >> 3) << 7; bn0 = (swz & 7) << 7;  // bn-inner
    ld = 1024;
    Ap = A0; Bp = B0;
  }

  f32x4 acc[4][4];
#pragma unroll
  for (int i = 0; i < 4; ++i)
#pragma unroll
    for (int j = 0; j < 4; ++j) acc[i][j] = f32x4{0.f, 0.f, 0.f, 0.f};

  auto stage = [&](int buf, int t) {
    const int k0 = koff + (t << 5) + kc;
    short* ab = lds + (buf << 13);
    short* bb = ab + 4096;
#pragma unroll
    for (int c = 0; c < 2; ++c) {
      const int un = wid * 2 + c;
      GLD_LDS(Ap + (size_t)(bm0 + (un << 4) + lrow) * ld + k0, ab + (un << 9));
      GLD_LDS(Bp + (size_t)(bn0 + (un << 4) + lrow) * ld + k0, bb + (un << 9));
    }
  };

  auto compute = [&](int buf) {
    const short* ab = lds + (buf << 13);
    const short* bb = ab + 4096;
    bf16x8 af[4], bfr[4];
#pragma unroll
    for (int i = 0; i < 4; ++i) {
      const int R = wm + (i << 4) + cl;
      af[i] = *(const bf16x8*)(ab + (R << 5) + ((khi ^ ((R >> 1) & 3)) << 3));
    }
#pragma unroll
    for (int j = 0; j < 4; ++j) {
      const int C = wn + (j << 4) + cl;
      bfr[j] = *(const bf16x8*)(bb + (C << 5) + ((khi ^ ((C >> 1) & 3)) << 3));
    }
#pragma unroll
    for (int i = 0; i < 4; ++i)
#pragma unroll
      for (int j = 0; j < 4; ++j)
        acc[i][j] = __builtin_amdgcn_mfma_f32_16x16x32_bf16(af[i], bfr[j], acc[i][j], 0, 0, 0);
  };

  stage(0, 0);
  stage(1, 1);
  asm volatile("s_waitcnt vmcnt(4)" ::: "memory");
  __builtin_amdgcn_s_barrier();
#pragma unroll 1
  for (int t = 0; t < 30; ++t) {
    stage((t + 2) & 3, t + 2);
    compute(t & 3);
    asm volatile("s_waitcnt vmcnt(4)" ::: "memory");
    __builtin_amdgcn_s_barrier();
  }
  compute(2);
  asm volatile("s_waitcnt vmcnt(0)" ::: "memory");
  __builtin_amdgcn_s_barrier();
  compute(3);

  if constexpr (MODE == 0) {
#pragma unroll
    for (int i = 0; i < 4; ++i)
#pragma unroll
      for (int j = 0; j < 4; ++j) {
        const int col = bn0 + wn + (j << 4) + cl;
        const int rowb = bm0 + wm + (i << 4) + (khi << 2);
#pragma unroll
        for (int r = 0; r < 4; ++r)
          of32[(size_t)(rowb + r) * 1024 + col] = acc[i][j][r];
      }
  } else if constexpr (MODE == 1) {
#pragma unroll
    for (int i = 0; i < 4; ++i)
#pragma unroll
      for (int j = 0; j < 4; ++j) {
        const int col = bn0 + wn + (j << 4) + cl;
        const int rowb = bm0 + wm + (i << 4) + (khi << 2);
#pragma unroll
        for (int r = 0; r < 4; ++r)
          obf[(size_t)(rowb + r) * 1024 + col] = f2bf(acc[i][j][r]);
      }
  } else if constexpr (MODE == 2) {
#pragma unroll
    for (int i = 0; i < 4; ++i) {
      const int rowb = bm0 + wm + (i << 4) + (khi << 2);
      s16x4 pk[4];
#pragma unroll
      for (int j = 0; j < 4; ++j) {
        const int col = bn0 + wn + (j << 4) + cl;
        const float rqc = cr0[b * 1024 + col];
#pragma unroll
        for (int r = 0; r < 4; ++r) pk[j][r] = f2bf(acc[i][j][r] + rqc);
#pragma unroll
        for (int r = 0; r < 4; ++r)
          obf[(size_t)(b * 4096 + rowb + r) * 1024 + col] = pk[j][r];
      }
#pragma unroll
      for (int r = 0; r < 4; ++r) {
        float sv = 0.f, sq = 0.f;
#pragma unroll
        for (int j = 0; j < 4; ++j) {
          const float fv = bf2f(pk[j][r]);
          sv += fv; sq += fv * fv;
        }
#pragma unroll
        for (int m = 1; m < 16; m <<= 1) {
          sv += __shfl_xor(sv, m);
          sq += __shfl_xor(sq, m);
        }
        if (cl == 0) {
          atomicAdd(&musum[b * 4096 + rowb + r], sv);
          atomicAdd(&sqsum[b * 4096 + rowb + r], sq);
        }
      }
    }
  } else {
#pragma unroll
    for (int i = 0; i < 4; ++i) {
      const int rowb = bm0 + wm + (i << 4) + (khi << 2);
      const float4 ms = *(const float4*)(musum + rowb);
      const float4 qs = *(const float4*)(sqsum + rowb);
      float mu[4], rs[4];
      mu[0] = ms.x * (1.0f / 1024.0f); mu[1] = ms.y * (1.0f / 1024.0f);
      mu[2] = ms.z * (1.0f / 1024.0f); mu[3] = ms.w * (1.0f / 1024.0f);
      rs[0] = rsqrtf(fmaxf(qs.x * (1.0f / 1024.0f) - mu[0] * mu[0], 0.f) + 1e-5f);
      rs[1] = rsqrtf(fmaxf(qs.y * (1.0f / 1024.0f) - mu[1] * mu[1], 0.f) + 1e-5f);
      rs[2] = rsqrtf(fmaxf(qs.z * (1.0f / 1024.0f) - mu[2] * mu[2], 0.f) + 1e-5f);
      rs[3] = rsqrtf(fmaxf(qs.w * (1.0f / 1024.0f) - mu[3] * mu[3], 0.f) + 1e-5f);
#pragma unroll
      for (int j = 0; j < 4; ++j) {
        const int col = bn0 + wn + (j << 4) + cl;
        const float uc = cr0[col];
        const float tc = cr1[col];
#pragma unroll
        for (int r = 0; r < 4; ++r)
          of32[(size_t)(rowb + r) * 1024 + col] = rs[r] * (acc[i][j][r] - mu[r] * uc) + tc;
      }
    }
  }
}

// ------- G~[b] = (Pg[0]+Pg[1]+Pg[2]+Pg[3]) / 4096 -> bf16 -------
__global__ __launch_bounds__(256)
void greduce_k(const float* __restrict__ Pg, short* __restrict__ G) {
  const int b = blockIdx.x >> 10;
  const int local = ((blockIdx.x & 1023) << 10) + (threadIdx.x << 2);
  float4 a = {0.f, 0.f, 0.f, 0.f};
#pragma unroll
  for (int kz = 0; kz < 4; ++kz) {
    const float4 v = *(const float4*)(Pg + (((size_t)((kz << 2) + b)) << 20) + local);
    a.x += v.x; a.y += v.y; a.z += v.z; a.w += v.w;
  }
  const float sc = 1.0f / 4096.0f;
  s16x4 o;
  o[0] = f2bf(a.x * sc); o[1] = f2bf(a.y * sc);
  o[2] = f2bf(a.z * sc); o[3] = f2bf(a.w * sc);
  *(s16x4*)(G + ((size_t)b << 20) + local) = o;
}

// ------- fused stage-2 + combine + weff: one block per (b,h) -------
__global__ __launch_bounds__(256)
void sw_k(const short* __restrict__ wt, const short* __restrict__ Tt,
          const float* __restrict__ u, const float* __restrict__ w,
          const float* __restrict__ bk, const float* __restrict__ bv,
          const short* __restrict__ wqn, const float* __restrict__ bq,
          short* __restrict__ Beff, float* __restrict__ rq) {
  __shared__ short Al[64 * 40];
  __shared__ short Bl[64 * 40];
  __shared__ short S[64][72];
  const int h = blockIdx.x & 15, b = blockIdx.x >> 4;
  const int tid = threadIdx.x, lane = tid & 63, wid = tid >> 6;
  const int srow = tid >> 2, sch = (tid & 3) << 3;
  const int cl = lane & 15, khi = lane >> 4;

  f32x4 acc2[2][4];
#pragma unroll
  for (int k = 0; k < 2; ++k)
#pragma unroll
    for (int j = 0; j < 4; ++j) acc2[k][j] = f32x4{0.f, 0.f, 0.f, 0.f};

#pragma unroll
  for (int k = 0; k < 2; ++k) {
    const short* Ap = wt + ((size_t)(1 + k) << 20) + ((size_t)(h * 64) << 10);
    const short* Bp = Tt + ((size_t)b << 21) + ((size_t)(k * 1024 + h * 64) << 10);
#pragma unroll 1
    for (int ns = 0; ns < 1024; ns += 32) {
      bf16x8 va = *(const bf16x8*)(Ap + ((size_t)srow << 10) + ns + sch);
      bf16x8 vb = *(const bf16x8*)(Bp + ((size_t)srow << 10) + ns + sch);
      __syncthreads();
      *(bf16x8*)(Al + srow * 40 + sch) = va;
      *(bf16x8*)(Bl + srow * 40 + sch) = vb;
      __syncthreads();
      bf16x8 a = *(const bf16x8*)(Al + (wid * 16 + cl) * 40 + (khi << 3));
#pragma unroll
      for (int j = 0; j < 4; ++j) {
        bf16x8 bb = *(const bf16x8*)(Bl + (j * 16 + cl) * 40 + (khi << 3));
        acc2[k][j] = __builtin_amdgcn_mfma_f32_16x16x32_bf16(a, bb, acc2[k][j], 0, 0, 0);
      }
    }
  }

  const int d0 = wid * 16 + (khi << 2);
  const float invN = 1.0f / 4096.0f;
#pragma unroll
  for (int j = 0; j < 4; ++j) {
    const int e = j * 16 + cl;
    s16x4 pk;
#pragma unroll
    for (int r = 0; r < 4; ++r) {
      const int d = d0 + r;
      float m[2];
#pragma unroll
      for (int k = 0; k < 2; ++k) {
        const float bkd = bk[k * 1024 + h * 64 + d];
        const float bve = bv[k * 1024 + h * 64 + e];
        const float ud = u[(k * 4 + b) * 1024 + h * 64 + d];
        const float we = w[(k * 4 + b) * 1024 + h * 64 + e];
        m[k] = acc2[k][j][r] + (ud * bve + bkd * we + 4096.f * bkd * bve) * invN;
      }
      pk[r] = f2bf(m[0] * m[1]);
    }
    *(s16x4*)(&S[e][d0]) = pk;
  }
  __syncthreads();

  if (wid == 0) {
    float acc = 0.f;
#pragma unroll 1
    for (int d = 0; d < 64; ++d) acc += bq[h * 64 + d] * bf2f(S[lane][d]);
    rq[b * 1024 + h * 64 + lane] = acc;
  }
  bf16x8 af[4][2];
#pragma unroll
  for (int mi = 0; mi < 4; ++mi)
#pragma unroll
    for (int kk = 0; kk < 2; ++kk)
      af[mi][kk] = *(const bf16x8*)(&S[mi * 16 + cl][kk * 32 + khi * 8]);
  const short* wq = wqn + h * 64;
  short* bdst = Beff + ((size_t)b << 20) + ((size_t)(h * 64) << 10);
#pragma unroll 1
  for (int nf = 0; nf < 16; ++nf) {
    const int c0 = wid * 256 + nf * 16;
    const bf16x8 bf0 = *(const bf16x8*)(wq + (size_t)(c0 + cl) * 1024 + khi * 8);
    const bf16x8 bf1 = *(const bf16x8*)(wq + (size_t)(c0 + cl) * 1024 + 32 + khi * 8);
    f32x4 a4[4];
#pragma unroll
    for (int mi = 0; mi < 4; ++mi) {
      a4[mi] = f32x4{0.f, 0.f, 0.f, 0.f};
      a4[mi] = __builtin_amdgcn_mfma_f32_16x16x32_bf16(af[mi][0], bf0, a4[mi], 0, 0, 0);
      a4[mi] = __builtin_amdgcn_mfma_f32_16x16x32_bf16(af[mi][1], bf1, a4[mi], 0, 0, 0);
    }
#pragma unroll
    for (int mi = 0; mi < 4; ++mi)
#pragma unroll
      for (int r = 0; r < 4; ++r)
        bdst[(size_t)(mi * 16 + khi * 4 + r) * 1024 + c0 + cl] = f2bf(a4[mi][r]);
  }
}

extern "C" void kernel_launch(void* const* d_in, const int* in_sizes, int n_in,
                              void* d_out, int out_size, void* d_ws, size_t ws_size,
                              hipStream_t stream) {
  const float* x = (const float*)d_in[0];
  const float* Wq = (const float*)d_in[1];
  const float* bq = (const float*)d_in[2];
  const float* Wk = (const float*)d_in[3];
  const float* bk = (const float*)d_in[4];
  const float* Wv = (const float*)d_in[5];
  const float* bv = (const float*)d_in[6];
  const float* Wo = (const float*)d_in[7];
  const float* bo = (const float*)d_in[8];
  const float* lng = (const float*)d_in[9];
  const float* lnb = (const float*)d_in[10];

  char* ws = (char*)d_ws;
  short* xb = (short*)(ws + 0);             // [0, 33554432)
  short* wt = (short*)(ws + 33554432);      // [33554432, 46137344)
  short* wqn = (short*)(ws + 46137344);     // [46137344, 48234496)
  short* Beff = (short*)(ws + 48234496);    // [48234496, 56623104)
  float* rq = (float*)(ws + 56623104);      // [56623104, 56639488)
  float* musum = (float*)(ws + 56639488);   // [56639488, 56705024)
  float* sqsum = (float*)(ws + 56705024);   // [56705024, 56770560)
  float* s = (float*)(ws + 56770560);       // [56770560, 56786944)  zeroed w/ musum
  float* u = (float*)(ws + 56786944);       // [56786944, 56819712)
  float* w = (float*)(ws + 56819712);       // [56819712, 56852480)
  float* uu = (float*)(ws + 56852480);      // [56852480, 56856576)
  float* tt = (float*)(ws + 56856576);      // [56856576, 56860672)
  short* xbT = (short*)(ws + 79691776);     // [79691776, 113246208) dead after gram
  short* Gt = (short*)(ws + 113246208);     // [113246208, 121634816)
  short* Tt = (short*)(ws + 121634816);     // [121634816, 138412032)
  float* Pg = (float*)(ws + 143351808);     // [143351808, 210460672)
  short* oat = xbT;

  hipMemsetAsync(musum, 0, 147456, stream);
  convt_k<<<dim3(16, 64, 4), 256, 0, stream>>>(x, xb, xbT, s);
  twc_k<<<dim3(32, 32, 6), dim3(32, 8), 0, stream>>>(Wq, Wk, Wv, Wo, lng, wt, wqn);
  gemv_k<<<dim3(16, 4, 4), 256, 0, stream>>>(wt, s, u, w);
  ut_k<<<16, 256, 0, stream>>>(Wo, lng, lnb, bo, uu, tt);

  g4_k<0><<<1024, 256, 65536, stream>>>(xbT, nullptr, nullptr, nullptr,
                                        nullptr, nullptr, nullptr, Pg);
  greduce_k<<<4096, 256, 0, stream>>>(Pg, Gt);
  g4_k<1><<<512, 256, 65536, stream>>>(wt + 3145728, Gt, nullptr, nullptr,
                                       nullptr, nullptr, Tt, nullptr);
  sw_k<<<64, 256, 0, stream>>>(wt, Tt, u, w, bk, bv, wqn, bq, Beff, rq);

  g4_k<2><<<1024, 256, 65536, stream>>>(xb, Beff, rq, nullptr,
                                        musum, sqsum, oat, nullptr);
  g4_k<3><<<1024, 256, 65536, stream>>>(oat, wt + 5242880, uu, tt,
                                        musum, sqsum, nullptr, (float*)d_out);
}

// Round 14
// 262.855 us; speedup vs baseline: 1.1230x; 1.0971x over previous
//
#include <hip/hip_runtime.h>
#include <hip/hip_bf16.h>

typedef __attribute__((ext_vector_type(8))) short bf16x8;
typedef __attribute__((ext_vector_type(4))) float f32x4;
typedef __attribute__((ext_vector_type(4))) short s16x4;

__device__ __forceinline__ short f2bf(float f) {
  union { float f; unsigned u; } v; v.f = f;
  unsigned r = v.u + 0x7fffu + ((v.u >> 16) & 1u);
  return (short)(r >> 16);
}

__device__ __forceinline__ float bf2f(short s) {
  union { float f; unsigned u; } v; v.u = ((unsigned)(unsigned short)s) << 16;
  return v.f;
}

#define GLD_LDS(g, l) __builtin_amdgcn_global_load_lds( \
    (const __attribute__((address_space(1))) void*)(g), \
    (__attribute__((address_space(3))) void*)(l), 16, 0, 0)

// ---- x -> xb + xbT (tiled transpose) + fused per-batch column sums (atomic) ----
__global__ __launch_bounds__(256)
void convt_k(const float* __restrict__ x, short* __restrict__ xb,
             short* __restrict__ xbT, float* __restrict__ s) {
  __shared__ short tile[64][72];
  __shared__ float red[4][64];
  const int b = blockIdx.z;
  const int n0 = blockIdx.y * 64;
  const int c0 = blockIdx.x * 64;
  const int t = threadIdx.x;
  const int nl = t >> 4;
  const int c4 = (t & 15) << 2;
  const float* xp = x + ((size_t)b * 4096 + n0) * 1024 + c0;
#pragma unroll
  for (int i = 0; i < 4; ++i) {
    const int n = nl + 16 * i;
    const float4 v = *(const float4*)(xp + (size_t)n * 1024 + c4);
    s16x4 o;
    o[0] = f2bf(v.x); o[1] = f2bf(v.y); o[2] = f2bf(v.z); o[3] = f2bf(v.w);
    *(s16x4*)(&xb[((size_t)b * 4096 + n0 + n) * 1024 + c0 + c4]) = o;
    *(s16x4*)(&tile[n][c4]) = o;
  }
  __syncthreads();
  const int cll = t >> 4;
  const int n4 = (t & 15) << 2;
#pragma unroll
  for (int i = 0; i < 4; ++i) {
    const int c = cll + 16 * i;
    s16x4 o;
    o[0] = tile[n4 + 0][c]; o[1] = tile[n4 + 1][c];
    o[2] = tile[n4 + 2][c]; o[3] = tile[n4 + 3][c];
    *(s16x4*)(&xbT[((size_t)b * 1024 + c0 + c) * 4096 + n0 + n4]) = o;
  }
  const int part = t >> 6, col = t & 63;
  float cs = 0.f;
#pragma unroll
  for (int i = 0; i < 16; ++i) cs += bf2f(tile[part * 16 + i][col]);
  red[part][col] = cs;
  __syncthreads();
  if (part == 0)
    atomicAdd(&s[b * 1024 + c0 + col],
              red[0][col] + red[1][col] + red[2][col] + red[3][col]);
}

// ------- weights: Wt[d][c] = W[c][d] (+I for z<5; g-fold z==5) -------
__global__ void twc_k(const float* __restrict__ Wq, const float* __restrict__ Wk,
                      const float* __restrict__ Wv, const float* __restrict__ Wo,
                      const float* __restrict__ lng, short* __restrict__ dst) {
  __shared__ float tile[32][33];
  const int z = blockIdx.z;
  const float* src = (z == 0) ? Wq
                   : (z == 1) ? Wk
                   : (z == 2) ? (Wk + 1048576)
                   : (z == 3) ? Wv
                   : (z == 4) ? (Wv + 1048576)
                   : Wo;
  short* d = dst + (size_t)z * 1048576;
  const int tx = threadIdx.x, ty = threadIdx.y;
  const int c0 = blockIdx.y * 32, d0 = blockIdx.x * 32;
#pragma unroll
  for (int i = 0; i < 4; ++i)
    tile[ty + i * 8][tx] = src[(size_t)(c0 + ty + i * 8) * 1024 + d0 + tx];
  __syncthreads();
#pragma unroll
  for (int i = 0; i < 4; ++i) {
    const int cc = c0 + tx;
    const int dd = d0 + ty + i * 8;
    float v = tile[tx][ty + i * 8];
    if (z < 5) {
      if (cc == dd) v += 1.0f;
    } else {
      v *= lng[cc];
    }
    d[(size_t)dd * 1024 + cc] = f2bf(v);
  }
}

// ------- u[k][b] = W~k^T s_b ; w[k][b] = W~v^T s_b -------
__global__ __launch_bounds__(256)
void gemv_k(const short* __restrict__ wt, const float* __restrict__ s,
            float* __restrict__ u, float* __restrict__ w) {
  const int z = blockIdx.z, b = blockIdx.y;
  const int lane = threadIdx.x & 63, wid = threadIdx.x >> 6;
  const short* W = wt + ((size_t)(z + 1) << 20);
  const float* sb = s + b * 1024;
  float* outp = (z < 2) ? (u + (z * 4 + b) * 1024) : (w + ((z - 2) * 4 + b) * 1024);
#pragma unroll 1
  for (int it = 0; it < 16; ++it) {
    const int d = blockIdx.x * 64 + wid * 16 + it;
    const short* row = W + (size_t)d * 1024 + lane * 16;
    float acc = 0.f;
#pragma unroll
    for (int j = 0; j < 16; ++j) acc += bf2f(row[j]) * sb[lane * 16 + j];
#pragma unroll
    for (int o = 32; o > 0; o >>= 1) acc += __shfl_down(acc, o);
    if (lane == 0) outp[d] = acc;
  }
}

// ------- uu[d] = sum_c g[c]Wo[c,d];  tt[d] = sum_c b[c]Wo[c,d] + bo[d] -------
__global__ __launch_bounds__(256)
void ut_k(const float* __restrict__ Wo, const float* __restrict__ lng,
          const float* __restrict__ lnb, const float* __restrict__ bo,
          float* __restrict__ u, float* __restrict__ t) {
  const int dl = threadIdx.x & 63;
  const int dd = blockIdx.x * 64 + dl;
  const int part = threadIdx.x >> 6;
  float su = 0.f, st = 0.f;
  for (int c = part * 256; c < part * 256 + 256; ++c) {
    const float w = Wo[(size_t)c * 1024 + dd];
    su += lng[c] * w;
    st += lnb[c] * w;
  }
  __shared__ float rs[4][64], rt[4][64];
  rs[part][dl] = su; rt[part][dl] = st;
  __syncthreads();
  if (part == 0) {
    su = rs[0][dl] + rs[1][dl] + rs[2][dl] + rs[3][dl];
    st = rt[0][dl] + rt[1][dl] + rt[2][dl] + rt[3][dl];
    u[dd] = su;
    t[dd] = st + bo[dd];
  }
}

// ---------------- fused gram + qproj (512 blocks -> 2/CU, measured 905 TF in R7) ----------------
// mode 0 (even blocks): gram  Pg[kz][b] = xbT_b chunk @ xbT_b chunk^T (fp32 partials)
// mode 1 (odd blocks):  qproj q = xb @ wt_q^T + bq (bf16)
// 256x256 tile, BK=32, 4-buffer counted-vmcnt pipeline, pair-line XOR LDS layout.
__global__ __launch_bounds__(512, 2)
void gramq_k(const short* __restrict__ xb, const short* __restrict__ xbT,
             const short* __restrict__ wtq, const float* __restrict__ bq,
             short* __restrict__ q, float* __restrict__ Pg) {
  extern __shared__ short lds[];  // 131072 B
  const int tid = threadIdx.x;
  const int lane = tid & 63;
  const int wv = tid >> 6;
  const int wm = wv >> 2;
  const int wn = wv & 3;
  const int mode = blockIdx.x & 1;
  const int id = blockIdx.x >> 1;                 // 0..255
  const int swz = ((id & 7) << 5) + (id >> 3);    // XCD-bijective on 256

  int bm0, bn0, ld, koff;
  const short *Ap, *Bp;
  float* po = nullptr;
  if (mode == 0) {
    const int kz = swz & 3, tl = (swz >> 2) & 15, b = swz >> 6;
    bm0 = (tl >> 2) << 8; bn0 = (tl & 3) << 8;
    ld = 4096; koff = kz << 10;
    Ap = xbT + ((size_t)b << 22);
    Bp = Ap;
    po = Pg + ((size_t)((kz << 2) + b) << 20);
  } else {
    bm0 = (swz & 63) << 8; bn0 = (swz >> 6) << 8;
    ld = 1024; koff = 0;
    Ap = xb; Bp = wtq;
  }

  const int lrow = ((lane >> 3) << 1) | ((lane >> 2) & 1);
  const int kc = ((lane & 3) ^ ((lane >> 3) & 3)) << 3;
  const int cl = lane & 15;
  const int khi = lane >> 4;

  f32x4 acc[8][4];
#pragma unroll
  for (int i = 0; i < 8; ++i)
#pragma unroll
    for (int j = 0; j < 4; ++j) acc[i][j] = f32x4{0.f, 0.f, 0.f, 0.f};

  auto stage = [&](int buf, int t) {
    const int k0 = koff + (t << 5) + kc;
    short* ab = lds + (buf << 14);
    short* bb = ab + 8192;
#pragma unroll
    for (int c = 0; c < 2; ++c) {
      const int un = wv * 2 + c;
      GLD_LDS(Ap + (size_t)(bm0 + (un << 4) + lrow) * ld + k0, ab + (un << 9));
      GLD_LDS(Bp + (size_t)(bn0 + (un << 4) + lrow) * ld + k0, bb + (un << 9));
    }
  };

  auto compute = [&](int buf) {
    const short* ab = lds + (buf << 14);
    const short* bb = ab + 8192;
    bf16x8 af[8], bfr[4];
#pragma unroll
    for (int i = 0; i < 8; ++i) {
      const int R = (wm << 7) + (i << 4) + cl;
      af[i] = *(const bf16x8*)(ab + (R << 5) + ((khi ^ ((R >> 1) & 3)) << 3));
    }
#pragma unroll
    for (int j = 0; j < 4; ++j) {
      const int C = (wn << 6) + (j << 4) + cl;
      bfr[j] = *(const bf16x8*)(bb + (C << 5) + ((khi ^ ((C >> 1) & 3)) << 3));
    }
#pragma unroll
    for (int i = 0; i < 8; ++i)
#pragma unroll
      for (int j = 0; j < 4; ++j)
        acc[i][j] = __builtin_amdgcn_mfma_f32_16x16x32_bf16(af[i], bfr[j], acc[i][j], 0, 0, 0);
  };

  stage(0, 0);
  stage(1, 1);
  asm volatile("s_waitcnt vmcnt(4)" ::: "memory");
  __builtin_amdgcn_s_barrier();
#pragma unroll 1
  for (int t = 0; t < 30; ++t) {
    stage((t + 2) & 3, t + 2);
    compute(t & 3);
    asm volatile("s_waitcnt vmcnt(4)" ::: "memory");
    __builtin_amdgcn_s_barrier();
  }
  compute(2);
  asm volatile("s_waitcnt vmcnt(0)" ::: "memory");
  __builtin_amdgcn_s_barrier();
  compute(3);

  if (mode == 0) {
#pragma unroll
    for (int i = 0; i < 8; ++i)
#pragma unroll
      for (int j = 0; j < 4; ++j) {
        const int col = bn0 + (wn << 6) + (j << 4) + cl;
        const int rowb = bm0 + (wm << 7) + (i << 4) + (khi << 2);
#pragma unroll
        for (int r = 0; r < 4; ++r)
          po[(size_t)(rowb + r) * 1024 + col] = acc[i][j][r];
      }
  } else {
#pragma unroll
    for (int i = 0; i < 8; ++i)
#pragma unroll
      for (int j = 0; j < 4; ++j) {
        const int col = bn0 + (wn << 6) + (j << 4) + cl;
        const int rowb = bm0 + (wm << 7) + (i << 4) + (khi << 2);
        const float bi = bq[col];
#pragma unroll
        for (int r = 0; r < 4; ++r)
          q[(size_t)(rowb + r) * 1024 + col] = f2bf(acc[i][j][r] + bi);
      }
  }
}

// ------- G~[b] = (Pg[0]+Pg[1]+Pg[2]+Pg[3]) / 4096 -> bf16 -------
__global__ __launch_bounds__(256)
void greduce_k(const float* __restrict__ Pg, short* __restrict__ G) {
  const int b = blockIdx.x >> 10;
  const int local = ((blockIdx.x & 1023) << 10) + (threadIdx.x << 2);
  float4 a = {0.f, 0.f, 0.f, 0.f};
#pragma unroll
  for (int kz = 0; kz < 4; ++kz) {
    const float4 v = *(const float4*)(Pg + (((size_t)((kz << 2) + b)) << 20) + local);
    a.x += v.x; a.y += v.y; a.z += v.z; a.w += v.w;
  }
  const float sc = 1.0f / 4096.0f;
  s16x4 o;
  o[0] = f2bf(a.x * sc); o[1] = f2bf(a.y * sc);
  o[2] = f2bf(a.z * sc); o[3] = f2bf(a.w * sc);
  *(s16x4*)(G + ((size_t)b << 20) + local) = o;
}

// ------- stage-1: Tt[b][e'][c] = sum_c' wt_v[e'][c'] * G~[b][c][c'] -------
// 128^2 tile, 4-buffer counted-vmcnt pipeline, 64KB LDS (verified R10).
__global__ __launch_bounds__(256, 2)
void gemm128_k(const short* __restrict__ A, const short* __restrict__ Bt,
               short* __restrict__ out) {
  extern __shared__ short lds[];  // 65536 B
  const int bid = blockIdx.x;
  const int swz = ((bid & 7) << 4) + (bid >> 3);
  const int bm0 = (swz >> 3) << 7;
  const int bn0 = (swz & 7) << 7;
  const short* Bp = Bt + ((size_t)blockIdx.y << 20);
  short* op = out + ((size_t)blockIdx.y << 21);
  const int tid = threadIdx.x, lane = tid & 63, wid = tid >> 6;
  const int wm = (wid >> 1) << 6, wn = (wid & 1) << 6;
  const int lrow = ((lane >> 3) << 1) | ((lane >> 2) & 1);
  const int kc = ((lane & 3) ^ ((lane >> 3) & 3)) << 3;
  const int cl = lane & 15, khi = lane >> 4;

  f32x4 acc[4][4];
#pragma unroll
  for (int i = 0; i < 4; ++i)
#pragma unroll
    for (int j = 0; j < 4; ++j) acc[i][j] = f32x4{0.f, 0.f, 0.f, 0.f};

  auto stage = [&](int buf, int t) {
    const int k0 = (t << 5) + kc;
    short* ab = lds + (buf << 13);
    short* bb = ab + 4096;
#pragma unroll
    for (int c = 0; c < 2; ++c) {
      const int un = wid * 2 + c;
      GLD_LDS(A + (size_t)(bm0 + (un << 4) + lrow) * 1024 + k0, ab + (un << 9));
      GLD_LDS(Bp + (size_t)(bn0 + (un << 4) + lrow) * 1024 + k0, bb + (un << 9));
    }
  };

  auto compute = [&](int buf) {
    const short* ab = lds + (buf << 13);
    const short* bb = ab + 4096;
    bf16x8 af[4], bfr[4];
#pragma unroll
    for (int i = 0; i < 4; ++i) {
      const int R = wm + (i << 4) + cl;
      af[i] = *(const bf16x8*)(ab + (R << 5) + ((khi ^ ((R >> 1) & 3)) << 3));
    }
#pragma unroll
    for (int j = 0; j < 4; ++j) {
      const int C = wn + (j << 4) + cl;
      bfr[j] = *(const bf16x8*)(bb + (C << 5) + ((khi ^ ((C >> 1) & 3)) << 3));
    }
#pragma unroll
    for (int i = 0; i < 4; ++i)
#pragma unroll
      for (int j = 0; j < 4; ++j)
        acc[i][j] = __builtin_amdgcn_mfma_f32_16x16x32_bf16(af[i], bfr[j], acc[i][j], 0, 0, 0);
  };

  stage(0, 0);
  stage(1, 1);
  asm volatile("s_waitcnt vmcnt(4)" ::: "memory");
  __builtin_amdgcn_s_barrier();
#pragma unroll 1
  for (int t = 0; t < 30; ++t) {
    stage((t + 2) & 3, t + 2);
    compute(t & 3);
    asm volatile("s_waitcnt vmcnt(4)" ::: "memory");
    __builtin_amdgcn_s_barrier();
  }
  compute(2);
  asm volatile("s_waitcnt vmcnt(0)" ::: "memory");
  __builtin_amdgcn_s_barrier();
  compute(3);

#pragma unroll
  for (int i = 0; i < 4; ++i)
#pragma unroll
    for (int j = 0; j < 4; ++j) {
      const int col = bn0 + wn + (j << 4) + cl;
      const int rowb = bm0 + wm + (i << 4) + (khi << 2);
#pragma unroll
      for (int r = 0; r < 4; ++r)
        op[(size_t)(rowb + r) * 1024 + col] = f2bf(acc[i][j][r]);
    }
}

// ------- fused stage-2 + combine: one block per (b,h) -> stt[bh][e][d] -------
__global__ __launch_bounds__(256)
void sc_k(const short* __restrict__ wt, const short* __restrict__ Tt,
          const float* __restrict__ u, const float* __restrict__ w,
          const float* __restrict__ bk, const float* __restrict__ bv,
          short* __restrict__ stt) {
  __shared__ short Al[64 * 40];
  __shared__ short Bl[64 * 40];
  const int h = blockIdx.x & 15, b = blockIdx.x >> 4;
  const int tid = threadIdx.x, lane = tid & 63, wid = tid >> 6;
  const int srow = tid >> 2, sch = (tid & 3) << 3;
  const int cl = lane & 15, khi = lane >> 4;

  f32x4 acc2[2][4];
#pragma unroll
  for (int k = 0; k < 2; ++k)
#pragma unroll
    for (int j = 0; j < 4; ++j) acc2[k][j] = f32x4{0.f, 0.f, 0.f, 0.f};

#pragma unroll
  for (int k = 0; k < 2; ++k) {
    const short* Ap = wt + ((size_t)(1 + k) << 20) + ((size_t)(h * 64) << 10);
    const short* Bp = Tt + ((size_t)b << 21) + ((size_t)(k * 1024 + h * 64) << 10);
#pragma unroll 1
    for (int ns = 0; ns < 1024; ns += 32) {
      bf16x8 va = *(const bf16x8*)(Ap + ((size_t)srow << 10) + ns + sch);
      bf16x8 vb = *(const bf16x8*)(Bp + ((size_t)srow << 10) + ns + sch);
      __syncthreads();
      *(bf16x8*)(Al + srow * 40 + sch) = va;
      *(bf16x8*)(Bl + srow * 40 + sch) = vb;
      __syncthreads();
      bf16x8 a = *(const bf16x8*)(Al + (wid * 16 + cl) * 40 + (khi << 3));
#pragma unroll
      for (int j = 0; j < 4; ++j) {
        bf16x8 bb = *(const bf16x8*)(Bl + (j * 16 + cl) * 40 + (khi << 3));
        acc2[k][j] = __builtin_amdgcn_mfma_f32_16x16x32_bf16(a, bb, acc2[k][j], 0, 0, 0);
      }
    }
  }

  // combine in-register -> stt[bh][e][d]  (M_k[d][e] with d = wid*16+khi*4+r, e = j*16+cl)
  const int d0 = wid * 16 + (khi << 2);
  const float invN = 1.0f / 4096.0f;
#pragma unroll
  for (int j = 0; j < 4; ++j) {
    const int e = j * 16 + cl;
    s16x4 pk;
#pragma unroll
    for (int r = 0; r < 4; ++r) {
      const int d = d0 + r;
      float m[2];
#pragma unroll
      for (int k = 0; k < 2; ++k) {
        const float bkd = bk[k * 1024 + h * 64 + d];
        const float bve = bv[k * 1024 + h * 64 + e];
        const float ud = u[(k * 4 + b) * 1024 + h * 64 + d];
        const float we = w[(k * 4 + b) * 1024 + h * 64 + e];
        m[k] = acc2[k][j][r] + (ud * bve + bkd * we + 4096.f * bkd * bve) * invN;
      }
      pk[r] = f2bf(m[0] * m[1]);
    }
    *(s16x4*)(stt + ((size_t)(b * 16 + h) << 12) + (e << 6) + d0) = pk;
  }
}

// ---------------- out_att = q @ state per (b,h) -> bf16 + LN-stat atomics ----------------
__global__ __launch_bounds__(256)
void attn_k(const short* __restrict__ q, const short* __restrict__ stt,
            short* __restrict__ oat, float* __restrict__ musum,
            float* __restrict__ sqsum) {
  __shared__ short Al[128 * 72];
  __shared__ short Bl[64 * 72];
  const int tid = threadIdx.x;
  const int lane = tid & 63;
  const int wid = tid >> 6;
  const int mc = blockIdx.x;
  const int bh = blockIdx.y;
  const int b = bh >> 4, h = bh & 15;
  const size_t qbase = ((size_t)(b * 4096 + mc * 128)) * 1024 + h * 64;
#pragma unroll
  for (int s = 0; s < 4; ++s) {
    const int idx = tid + s * 256;
    const int row = idx >> 3, cc = (idx & 7) << 3;
    *(bf16x8*)(Al + row * 72 + cc) = *(const bf16x8*)(q + qbase + (size_t)row * 1024 + cc);
  }
#pragma unroll
  for (int s = 0; s < 2; ++s) {
    const int idx = tid + s * 256;
    const int row = idx >> 3, cc = (idx & 7) << 3;
    *(bf16x8*)(Bl + row * 72 + cc) = *(const bf16x8*)(stt + (bh << 12) + (row << 6) + cc);
  }
  __syncthreads();
  f32x4 acc[2][4];
#pragma unroll
  for (int i = 0; i < 2; ++i)
#pragma unroll
    for (int j = 0; j < 4; ++j) acc[i][j] = f32x4{0.f, 0.f, 0.f, 0.f};
#pragma unroll
  for (int ks = 0; ks < 2; ++ks) {
    bf16x8 a0 = *(const bf16x8*)(Al + (wid * 32 + (lane & 15)) * 72 + ks * 32 + ((lane >> 4) << 3));
    bf16x8 a1 = *(const bf16x8*)(Al + (wid * 32 + 16 + (lane & 15)) * 72 + ks * 32 + ((lane >> 4) << 3));
#pragma unroll
    for (int j = 0; j < 4; ++j) {
      bf16x8 bb = *(const bf16x8*)(Bl + (j * 16 + (lane & 15)) * 72 + ks * 32 + ((lane >> 4) << 3));
      acc[0][j] = __builtin_amdgcn_mfma_f32_16x16x32_bf16(a0, bb, acc[0][j], 0, 0, 0);
      acc[1][j] = __builtin_amdgcn_mfma_f32_16x16x32_bf16(a1, bb, acc[1][j], 0, 0, 0);
    }
  }
  const int r0 = wid * 32 + ((lane >> 4) << 2);
  const int cl = lane & 15;
#pragma unroll
  for (int i = 0; i < 2; ++i) {
    s16x4 pk[4];
#pragma unroll
    for (int j = 0; j < 4; ++j) {
#pragma unroll
      for (int r = 0; r < 4; ++r) pk[j][r] = f2bf(acc[i][j][r]);
#pragma unroll
      for (int r = 0; r < 4; ++r) {
        const int row = b * 4096 + mc * 128 + r0 + i * 16 + r;
        oat[(size_t)row * 1024 + h * 64 + j * 16 + cl] = pk[j][r];
      }
    }
#pragma unroll
    for (int r = 0; r < 4; ++r) {
      float sv = 0.f, sq = 0.f;
#pragma unroll
      for (int j = 0; j < 4; ++j) {
        const float fv = bf2f(pk[j][r]);
        sv += fv; sq += fv * fv;
      }
#pragma unroll
      for (int m = 1; m < 16; m <<= 1) {
        sv += __shfl_xor(sv, m);
        sq += __shfl_xor(sq, m);
      }
      if (cl == 0) {
        const int row = b * 4096 + mc * 128 + r0 + i * 16 + r;
        atomicAdd(&musum[row], sv);
        atomicAdd(&sqsum[row], sq);
      }
    }
  }
}

// ---------------- final GEMM with folded LayerNorm (mu/rstd from atomic sums) ----------------
__global__ __launch_bounds__(512, 2)
void gemmo_k(const short* __restrict__ A, const short* __restrict__ WT,
             const float* __restrict__ musum, const float* __restrict__ sqsum,
             const float* __restrict__ uu, const float* __restrict__ tt,
             float* __restrict__ fout) {
  extern __shared__ short lds[];
  const int tid = threadIdx.x;
  const int lane = tid & 63;
  const int wv = tid >> 6;
  const int wm = wv >> 2;
  const int wn = wv & 3;
  const int swz = ((blockIdx.x & 7) << 5) + (blockIdx.x >> 3);
  const int bm0 = (swz >> 2) << 8;   // bn-inner: A-slab L2 reuse
  const int bn0 = (swz & 3) << 8;

  const int lrow = ((lane >> 3) << 1) | ((lane >> 2) & 1);
  const int kc = ((lane & 3) ^ ((lane >> 3) & 3)) << 3;
  const int cl = lane & 15;
  const int khi = lane >> 4;

  f32x4 acc[8][4];
#pragma unroll
  for (int i = 0; i < 8; ++i)
#pragma unroll
    for (int j = 0; j < 4; ++j) acc[i][j] = f32x4{0.f, 0.f, 0.f, 0.f};

  auto stage = [&](int buf, int t) {
    const int k0 = (t << 5) + kc;
    short* ab = lds + (buf << 14);
    short* bb = ab + 8192;
#pragma unroll
    for (int c = 0; c < 2; ++c) {
      const int un = wv * 2 + c;
      GLD_LDS(A + (size_t)(bm0 + (un << 4) + lrow) * 1024 + k0, ab + (un << 9));
      GLD_LDS(WT + (size_t)(bn0 + (un << 4) + lrow) * 1024 + k0, bb + (un << 9));
    }
  };

  auto compute = [&](int buf) {
    const short* ab = lds + (buf << 14);
    const short* bb = ab + 8192;
    bf16x8 af[8], bfr[4];
#pragma unroll
    for (int i = 0; i < 8; ++i) {
      const int R = (wm << 7) + (i << 4) + cl;
      af[i] = *(const bf16x8*)(ab + (R << 5) + ((khi ^ ((R >> 1) & 3)) << 3));
    }
#pragma unroll
    for (int j = 0; j < 4; ++j) {
      const int C = (wn << 6) + (j << 4) + cl;
      bfr[j] = *(const bf16x8*)(bb + (C << 5) + ((khi ^ ((C >> 1) & 3)) << 3));
    }
#pragma unroll
    for (int i = 0; i < 8; ++i)
#pragma unroll
      for (int j = 0; j < 4; ++j)
        acc[i][j] = __builtin_amdgcn_mfma_f32_16x16x32_bf16(af[i], bfr[j], acc[i][j], 0, 0, 0);
  };

  stage(0, 0);
  stage(1, 1);
  asm volatile("s_waitcnt vmcnt(4)" ::: "memory");
  __builtin_amdgcn_s_barrier();
#pragma unroll 1
  for (int t = 0; t < 30; ++t) {
    stage((t + 2) & 3, t + 2);
    compute(t & 3);
    asm volatile("s_waitcnt vmcnt(4)" ::: "memory");
    __builtin_amdgcn_s_barrier();
  }
  compute(2);
  asm volatile("s_waitcnt vmcnt(0)" ::: "memory");
  __builtin_amdgcn_s_barrier();
  compute(3);

#pragma unroll
  for (int i = 0; i < 8; ++i) {
    const int rowb = bm0 + (wm << 7) + (i << 4) + (khi << 2);
    const float4 ms = *(const float4*)(musum + rowb);
    const float4 qs = *(const float4*)(sqsum + rowb);
    float mu[4], rs[4];
    mu[0] = ms.x * (1.0f / 1024.0f); mu[1] = ms.y * (1.0f / 1024.0f);
    mu[2] = ms.z * (1.0f / 1024.0f); mu[3] = ms.w * (1.0f / 1024.0f);
    rs[0] = rsqrtf(fmaxf(qs.x * (1.0f / 1024.0f) - mu[0] * mu[0], 0.f) + 1e-5f);
    rs[1] = rsqrtf(fmaxf(qs.y * (1.0f / 1024.0f) - mu[1] * mu[1], 0.f) + 1e-5f);
    rs[2] = rsqrtf(fmaxf(qs.z * (1.0f / 1024.0f) - mu[2] * mu[2], 0.f) + 1e-5f);
    rs[3] = rsqrtf(fmaxf(qs.w * (1.0f / 1024.0f) - mu[3] * mu[3], 0.f) + 1e-5f);
#pragma unroll
    for (int j = 0; j < 4; ++j) {
      const int col = bn0 + (wn << 6) + (j << 4) + cl;
      const float uc = uu[col];
      const float tc = tt[col];
#pragma unroll
      for (int r = 0; r < 4; ++r)
        fout[(size_t)(rowb + r) * 1024 + col] = rs[r] * (acc[i][j][r] - mu[r] * uc) + tc;
    }
  }
}

extern "C" void kernel_launch(void* const* d_in, const int* in_sizes, int n_in,
                              void* d_out, int out_size, void* d_ws, size_t ws_size,
                              hipStream_t stream) {
  const float* x = (const float*)d_in[0];
  const float* Wq = (const float*)d_in[1];
  const float* bq = (const float*)d_in[2];
  const float* Wk = (const float*)d_in[3];
  const float* bk = (const float*)d_in[4];
  const float* Wv = (const float*)d_in[5];
  const float* bv = (const float*)d_in[6];
  const float* Wo = (const float*)d_in[7];
  const float* bo = (const float*)d_in[8];
  const float* lng = (const float*)d_in[9];
  const float* lnb = (const float*)d_in[10];

  char* ws = (char*)d_ws;
  // ---- verified non-overlapping layout ----
  short* xb = (short*)(ws + 0);             // [0, 33554432)
  short* wt = (short*)(ws + 33554432);      // [33554432, 46137344)
  short* q = (short*)(ws + 46137344);       // [46137344, 79691776)
  short* xbT = (short*)(ws + 79691776);     // [79691776, 113246208) dead after gram -> oat
  short* Gt = (short*)(ws + 113246208);     // [113246208, 121634816)
  short* Tt = (short*)(ws + 121634816);     // [121634816, 138412032)
  short* stt = (short*)(ws + 138412032);    // [138412032, 138936320)
  float* u = (float*)(ws + 138936320);      // [138936320, 138969088)
  float* w = (float*)(ws + 138969088);      // [138969088, 139001856)
  float* uu = (float*)(ws + 139001856);     // [139001856, 139005952)
  float* tt = (float*)(ws + 139005952);     // [139005952, 139010048)
  float* s = (float*)(ws + 139010048);      // [139010048, 139026432)  zeroed
  float* musum = (float*)(ws + 139026432);  // [139026432, 139091968)  zeroed
  float* sqsum = (float*)(ws + 139091968);  // [139091968, 139157504)  zeroed
  float* Pg = (float*)(ws + 143351808);     // [143351808, 210460672)
  short* oat = xbT;

  hipMemsetAsync(s, 0, 147456, stream);  // s + musum + sqsum contiguous 144KB
  convt_k<<<dim3(16, 64, 4), 256, 0, stream>>>(x, xb, xbT, s);
  twc_k<<<dim3(32, 32, 6), dim3(32, 8), 0, stream>>>(Wq, Wk, Wv, Wo, lng, wt);
  gemv_k<<<dim3(16, 4, 4), 256, 0, stream>>>(wt, s, u, w);
  ut_k<<<16, 256, 0, stream>>>(Wo, lng, lnb, bo, uu, tt);

  // fused: Gram partials (even blocks) + q projection (odd blocks) — 905 TF in R7
  gramq_k<<<512, 512, 131072, stream>>>(xb, xbT, wt, bq, q, Pg);
  greduce_k<<<4096, 256, 0, stream>>>(Pg, Gt);
  gemm128_k<<<dim3(128, 4), 256, 65536, stream>>>(wt + 3145728, Gt, Tt);
  sc_k<<<64, 256, 0, stream>>>(wt, Tt, u, w, bk, bv, stt);

  attn_k<<<dim3(32, 64), 256, 0, stream>>>(q, stt, oat, musum, sqsum);
  gemmo_k<<<256, 512, 131072, stream>>>(oat, wt + 5242880, musum, sqsum, uu, tt,
                                        (float*)d_out);
}

// Round 15
// 256.748 us; speedup vs baseline: 1.1497x; 1.0238x over previous
//
#include <hip/hip_runtime.h>
#include <hip/hip_bf16.h>

typedef __attribute__((ext_vector_type(8))) short bf16x8;
typedef __attribute__((ext_vector_type(4))) float f32x4;
typedef __attribute__((ext_vector_type(4))) short s16x4;

__device__ __forceinline__ short f2bf(float f) {
  union { float f; unsigned u; } v; v.f = f;
  unsigned r = v.u + 0x7fffu + ((v.u >> 16) & 1u);
  return (short)(r >> 16);
}

__device__ __forceinline__ float bf2f(short s) {
  union { float f; unsigned u; } v; v.u = ((unsigned)(unsigned short)s) << 16;
  return v.f;
}

#define GLD_LDS(g, l) __builtin_amdgcn_global_load_lds( \
    (const __attribute__((address_space(1))) void*)(g), \
    (__attribute__((address_space(3))) void*)(l), 16, 0, 0)

// ---- x -> xb + xbT (tiled transpose) + fused per-batch column sums (atomic) ----
__global__ __launch_bounds__(256)
void convt_k(const float* __restrict__ x, short* __restrict__ xb,
             short* __restrict__ xbT, float* __restrict__ s) {
  __shared__ short tile[64][72];
  __shared__ float red[4][64];
  const int b = blockIdx.z;
  const int n0 = blockIdx.y * 64;
  const int c0 = blockIdx.x * 64;
  const int t = threadIdx.x;
  const int nl = t >> 4;
  const int c4 = (t & 15) << 2;
  const float* xp = x + ((size_t)b * 4096 + n0) * 1024 + c0;
#pragma unroll
  for (int i = 0; i < 4; ++i) {
    const int n = nl + 16 * i;
    const float4 v = *(const float4*)(xp + (size_t)n * 1024 + c4);
    s16x4 o;
    o[0] = f2bf(v.x); o[1] = f2bf(v.y); o[2] = f2bf(v.z); o[3] = f2bf(v.w);
    *(s16x4*)(&xb[((size_t)b * 4096 + n0 + n) * 1024 + c0 + c4]) = o;
    *(s16x4*)(&tile[n][c4]) = o;
  }
  __syncthreads();
  const int cll = t >> 4;
  const int n4 = (t & 15) << 2;
#pragma unroll
  for (int i = 0; i < 4; ++i) {
    const int c = cll + 16 * i;
    s16x4 o;
    o[0] = tile[n4 + 0][c]; o[1] = tile[n4 + 1][c];
    o[2] = tile[n4 + 2][c]; o[3] = tile[n4 + 3][c];
    *(s16x4*)(&xbT[((size_t)b * 1024 + c0 + c) * 4096 + n0 + n4]) = o;
  }
  const int part = t >> 6, col = t & 63;
  float cs = 0.f;
#pragma unroll
  for (int i = 0; i < 16; ++i) cs += bf2f(tile[part * 16 + i][col]);
  red[part][col] = cs;
  __syncthreads();
  if (part == 0)
    atomicAdd(&s[b * 1024 + c0 + col],
              red[0][col] + red[1][col] + red[2][col] + red[3][col]);
}

// ------- weights: Wt[d][c] = W[c][d] (+I for z<5; g-fold z==5) -------
__global__ void twc_k(const float* __restrict__ Wq, const float* __restrict__ Wk,
                      const float* __restrict__ Wv, const float* __restrict__ Wo,
                      const float* __restrict__ lng, short* __restrict__ dst) {
  __shared__ float tile[32][33];
  const int z = blockIdx.z;
  const float* src = (z == 0) ? Wq
                   : (z == 1) ? Wk
                   : (z == 2) ? (Wk + 1048576)
                   : (z == 3) ? Wv
                   : (z == 4) ? (Wv + 1048576)
                   : Wo;
  short* d = dst + (size_t)z * 1048576;
  const int tx = threadIdx.x, ty = threadIdx.y;
  const int c0 = blockIdx.y * 32, d0 = blockIdx.x * 32;
#pragma unroll
  for (int i = 0; i < 4; ++i)
    tile[ty + i * 8][tx] = src[(size_t)(c0 + ty + i * 8) * 1024 + d0 + tx];
  __syncthreads();
#pragma unroll
  for (int i = 0; i < 4; ++i) {
    const int cc = c0 + tx;
    const int dd = d0 + ty + i * 8;
    float v = tile[tx][ty + i * 8];
    if (z < 5) {
      if (cc == dd) v += 1.0f;
    } else {
      v *= lng[cc];
    }
    d[(size_t)dd * 1024 + cc] = f2bf(v);
  }
}

// ------- u[k][b] = W~k^T s_b ; w[k][b] = W~v^T s_b -------
__global__ __launch_bounds__(256)
void gemv_k(const short* __restrict__ wt, const float* __restrict__ s,
            float* __restrict__ u, float* __restrict__ w) {
  const int z = blockIdx.z, b = blockIdx.y;
  const int lane = threadIdx.x & 63, wid = threadIdx.x >> 6;
  const short* W = wt + ((size_t)(z + 1) << 20);
  const float* sb = s + b * 1024;
  float* outp = (z < 2) ? (u + (z * 4 + b) * 1024) : (w + ((z - 2) * 4 + b) * 1024);
#pragma unroll 1
  for (int it = 0; it < 16; ++it) {
    const int d = blockIdx.x * 64 + wid * 16 + it;
    const short* row = W + (size_t)d * 1024 + lane * 16;
    float acc = 0.f;
#pragma unroll
    for (int j = 0; j < 16; ++j) acc += bf2f(row[j]) * sb[lane * 16 + j];
#pragma unroll
    for (int o = 32; o > 0; o >>= 1) acc += __shfl_down(acc, o);
    if (lane == 0) outp[d] = acc;
  }
}

// ------- uu[d] = sum_c g[c]Wo[c,d];  tt[d] = sum_c b[c]Wo[c,d] + bo[d] -------
__global__ __launch_bounds__(256)
void ut_k(const float* __restrict__ Wo, const float* __restrict__ lng,
          const float* __restrict__ lnb, const float* __restrict__ bo,
          float* __restrict__ u, float* __restrict__ t) {
  const int dl = threadIdx.x & 63;
  const int dd = blockIdx.x * 64 + dl;
  const int part = threadIdx.x >> 6;
  float su = 0.f, st = 0.f;
  for (int c = part * 256; c < part * 256 + 256; ++c) {
    const float w = Wo[(size_t)c * 1024 + dd];
    su += lng[c] * w;
    st += lnb[c] * w;
  }
  __shared__ float rs[4][64], rt[4][64];
  rs[part][dl] = su; rt[part][dl] = st;
  __syncthreads();
  if (part == 0) {
    su = rs[0][dl] + rs[1][dl] + rs[2][dl] + rs[3][dl];
    st = rt[0][dl] + rt[1][dl] + rt[2][dl] + rt[3][dl];
    u[dd] = su;
    t[dd] = st + bo[dd];
  }
}

// ---------------- fused gram(triangle, split-K=6) + qproj — 496 interleaved blocks ----------------
// gram (even ids < 480): Pg[chunk g] = 256x256 fp32 partial of upper-tri tile (ti,tj),
//   K-chunk sp of 6 (21/21/22/21/21/22 BK-tiles). qproj (others): q = xb@wtq^T + bq.
// 256x256 tile, BK=32, 4-buffer counted-vmcnt pipeline, runtime trip count.
__global__ __launch_bounds__(512, 2)
void gramq_k(const short* __restrict__ xb, const short* __restrict__ xbT,
             const short* __restrict__ wtq, const float* __restrict__ bq,
             short* __restrict__ q, float* __restrict__ Pg) {
  extern __shared__ short lds[];  // 131072 B
  const int tid = threadIdx.x;
  const int lane = tid & 63;
  const int wv = tid >> 6;
  const int wm = wv >> 2;
  const int wn = wv & 3;

  const int id = blockIdx.x;  // 0..495
  bool isgram;
  int g = 0, qid = 0;
  if (id < 480) {
    if ((id & 1) == 0) { isgram = true; g = id >> 1; }
    else { isgram = false; qid = id >> 1; }
  } else {
    isgram = false; qid = 240 + (id - 480);
  }

  int bm0, bn0, ld, koff, nt;
  const short *Ap, *Bp;
  float* po = nullptr;
  if (isgram) {
    const int p = g / 6, sp = g - p * 6;   // pair 0..39, split 0..5
    const int b = p / 10;
    int t = p - b * 10, ti = 0;
    while (t >= 4 - ti) { t -= 4 - ti; ++ti; }
    const int tj = ti + t;
    const int kst[7] = {0, 21, 42, 64, 85, 106, 128};
    bm0 = ti << 8; bn0 = tj << 8;
    ld = 4096;
    koff = kst[sp] << 5;
    nt = kst[sp + 1] - kst[sp];
    Ap = xbT + ((size_t)b << 22);
    Bp = Ap;
    po = Pg + ((size_t)g << 16);
  } else {
    const int swz = ((qid & 7) << 5) + (qid >> 3);  // XCD-bijective on 256
    bm0 = (swz & 63) << 8; bn0 = (swz >> 6) << 8;
    ld = 1024; koff = 0; nt = 32;
    Ap = xb; Bp = wtq;
  }

  const int lrow = ((lane >> 3) << 1) | ((lane >> 2) & 1);
  const int kc = ((lane & 3) ^ ((lane >> 3) & 3)) << 3;
  const int cl = lane & 15;
  const int khi = lane >> 4;

  f32x4 acc[8][4];
#pragma unroll
  for (int i = 0; i < 8; ++i)
#pragma unroll
    for (int j = 0; j < 4; ++j) acc[i][j] = f32x4{0.f, 0.f, 0.f, 0.f};

  auto stage = [&](int buf, int t) {
    const int k0 = koff + (t << 5) + kc;
    short* ab = lds + (buf << 14);
    short* bb = ab + 8192;
#pragma unroll
    for (int c = 0; c < 2; ++c) {
      const int un = wv * 2 + c;
      GLD_LDS(Ap + (size_t)(bm0 + (un << 4) + lrow) * ld + k0, ab + (un << 9));
      GLD_LDS(Bp + (size_t)(bn0 + (un << 4) + lrow) * ld + k0, bb + (un << 9));
    }
  };

  auto compute = [&](int buf) {
    const short* ab = lds + (buf << 14);
    const short* bb = ab + 8192;
    bf16x8 af[8], bfr[4];
#pragma unroll
    for (int i = 0; i < 8; ++i) {
      const int R = (wm << 7) + (i << 4) + cl;
      af[i] = *(const bf16x8*)(ab + (R << 5) + ((khi ^ ((R >> 1) & 3)) << 3));
    }
#pragma unroll
    for (int j = 0; j < 4; ++j) {
      const int C = (wn << 6) + (j << 4) + cl;
      bfr[j] = *(const bf16x8*)(bb + (C << 5) + ((khi ^ ((C >> 1) & 3)) << 3));
    }
#pragma unroll
    for (int i = 0; i < 8; ++i)
#pragma unroll
      for (int j = 0; j < 4; ++j)
        acc[i][j] = __builtin_amdgcn_mfma_f32_16x16x32_bf16(af[i], bfr[j], acc[i][j], 0, 0, 0);
  };

  stage(0, 0);
  stage(1, 1);
  asm volatile("s_waitcnt vmcnt(4)" ::: "memory");
  __builtin_amdgcn_s_barrier();
#pragma unroll 1
  for (int t = 0; t < nt - 2; ++t) {
    stage((t + 2) & 3, t + 2);
    compute(t & 3);
    asm volatile("s_waitcnt vmcnt(4)" ::: "memory");
    __builtin_amdgcn_s_barrier();
  }
  compute((nt - 2) & 3);
  asm volatile("s_waitcnt vmcnt(0)" ::: "memory");
  __builtin_amdgcn_s_barrier();
  compute((nt - 1) & 3);

  if (isgram) {
    // local 256x256 fp32 chunk
#pragma unroll
    for (int i = 0; i < 8; ++i)
#pragma unroll
      for (int j = 0; j < 4; ++j) {
        const int col = (wn << 6) + (j << 4) + cl;
        const int rowb = (wm << 7) + (i << 4) + (khi << 2);
#pragma unroll
        for (int r = 0; r < 4; ++r)
          po[(size_t)(rowb + r) * 256 + col] = acc[i][j][r];
      }
  } else {
#pragma unroll
    for (int i = 0; i < 8; ++i)
#pragma unroll
      for (int j = 0; j < 4; ++j) {
        const int col = bn0 + (wn << 6) + (j << 4) + cl;
        const int rowb = bm0 + (wm << 7) + (i << 4) + (khi << 2);
        const float bi = bq[col];
#pragma unroll
        for (int r = 0; r < 4; ++r)
          q[(size_t)(rowb + r) * 1024 + col] = f2bf(acc[i][j][r] + bi);
      }
  }
}

// ------- reduce 6 K-chunks per upper tile, write Gt tile + mirrored transpose -------
__global__ __launch_bounds__(256)
void gred6_k(const float* __restrict__ Pg, short* __restrict__ G) {
  __shared__ short tile[64][72];
  const int bid = blockIdx.x;          // 640 = 40 pairs x 16 sub-64-tiles
  const int p = bid >> 4;
  const int st = bid & 15;
  const int b = p / 10;
  int t = p - b * 10, ti = 0;
  while (t >= 4 - ti) { t -= 4 - ti; ++ti; }
  const int tj = ti + t;
  const int sr = st >> 2, sc = st & 3;
  const int r = threadIdx.x >> 2;
  const int c0 = (threadIdx.x & 3) << 4;
  float acc[16];
#pragma unroll
  for (int qq = 0; qq < 16; ++qq) acc[qq] = 0.f;
#pragma unroll
  for (int s = 0; s < 6; ++s) {
    const float* base = Pg + ((size_t)(p * 6 + s) << 16)
                      + (size_t)(sr * 64 + r) * 256 + sc * 64 + c0;
#pragma unroll
    for (int q4 = 0; q4 < 4; ++q4) {
      const float4 v = ((const float4*)base)[q4];
      acc[q4 * 4 + 0] += v.x; acc[q4 * 4 + 1] += v.y;
      acc[q4 * 4 + 2] += v.z; acc[q4 * 4 + 3] += v.w;
    }
  }
  const float scf = 1.0f / 4096.0f;
  short* gb = G + ((size_t)b << 20);
  const int row = ti * 256 + sr * 64 + r;
  const int colb = tj * 256 + sc * 64 + c0;
#pragma unroll
  for (int q4 = 0; q4 < 4; ++q4) {
    s16x4 o;
#pragma unroll
    for (int e = 0; e < 4; ++e) {
      o[e] = f2bf(acc[q4 * 4 + e] * scf);
      tile[r][c0 + q4 * 4 + e] = o[e];
    }
    *(s16x4*)(gb + (size_t)row * 1024 + colb + q4 * 4) = o;
  }
  __syncthreads();
  if (ti != tj) {
    const int row2 = tj * 256 + sc * 64 + r;
    const int col2 = ti * 256 + sr * 64 + c0;
#pragma unroll
    for (int q4 = 0; q4 < 4; ++q4) {
      s16x4 o;
#pragma unroll
      for (int e = 0; e < 4; ++e) o[e] = tile[c0 + q4 * 4 + e][r];
      *(s16x4*)(gb + (size_t)row2 * 1024 + col2 + q4 * 4) = o;
    }
  }
}

// ------- stage-1: Tt[b][e'][c] = sum_c' wt_v[e'][c'] * G~[b][c][c'] -------
__global__ __launch_bounds__(256, 2)
void gemm128_k(const short* __restrict__ A, const short* __restrict__ Bt,
               short* __restrict__ out) {
  extern __shared__ short lds[];  // 65536 B
  const int bid = blockIdx.x;
  const int swz = ((bid & 7) << 4) + (bid >> 3);
  const int bm0 = (swz >> 3) << 7;
  const int bn0 = (swz & 7) << 7;
  const short* Bp = Bt + ((size_t)blockIdx.y << 20);
  short* op = out + ((size_t)blockIdx.y << 21);
  const int tid = threadIdx.x, lane = tid & 63, wid = tid >> 6;
  const int wm = (wid >> 1) << 6, wn = (wid & 1) << 6;
  const int lrow = ((lane >> 3) << 1) | ((lane >> 2) & 1);
  const int kc = ((lane & 3) ^ ((lane >> 3) & 3)) << 3;
  const int cl = lane & 15, khi = lane >> 4;

  f32x4 acc[4][4];
#pragma unroll
  for (int i = 0; i < 4; ++i)
#pragma unroll
    for (int j = 0; j < 4; ++j) acc[i][j] = f32x4{0.f, 0.f, 0.f, 0.f};

  auto stage = [&](int buf, int t) {
    const int k0 = (t << 5) + kc;
    short* ab = lds + (buf << 13);
    short* bb = ab + 4096;
#pragma unroll
    for (int c = 0; c < 2; ++c) {
      const int un = wid * 2 + c;
      GLD_LDS(A + (size_t)(bm0 + (un << 4) + lrow) * 1024 + k0, ab + (un << 9));
      GLD_LDS(Bp + (size_t)(bn0 + (un << 4) + lrow) * 1024 + k0, bb + (un << 9));
    }
  };

  auto compute = [&](int buf) {
    const short* ab = lds + (buf << 13);
    const short* bb = ab + 4096;
    bf16x8 af[4], bfr[4];
#pragma unroll
    for (int i = 0; i < 4; ++i) {
      const int R = wm + (i << 4) + cl;
      af[i] = *(const bf16x8*)(ab + (R << 5) + ((khi ^ ((R >> 1) & 3)) << 3));
    }
#pragma unroll
    for (int j = 0; j < 4; ++j) {
      const int C = wn + (j << 4) + cl;
      bfr[j] = *(const bf16x8*)(bb + (C << 5) + ((khi ^ ((C >> 1) & 3)) << 3));
    }
#pragma unroll
    for (int i = 0; i < 4; ++i)
#pragma unroll
      for (int j = 0; j < 4; ++j)
        acc[i][j] = __builtin_amdgcn_mfma_f32_16x16x32_bf16(af[i], bfr[j], acc[i][j], 0, 0, 0);
  };

  stage(0, 0);
  stage(1, 1);
  asm volatile("s_waitcnt vmcnt(4)" ::: "memory");
  __builtin_amdgcn_s_barrier();
#pragma unroll 1
  for (int t = 0; t < 30; ++t) {
    stage((t + 2) & 3, t + 2);
    compute(t & 3);
    asm volatile("s_waitcnt vmcnt(4)" ::: "memory");
    __builtin_amdgcn_s_barrier();
  }
  compute(2);
  asm volatile("s_waitcnt vmcnt(0)" ::: "memory");
  __builtin_amdgcn_s_barrier();
  compute(3);

#pragma unroll
  for (int i = 0; i < 4; ++i)
#pragma unroll
    for (int j = 0; j < 4; ++j) {
      const int col = bn0 + wn + (j << 4) + cl;
      const int rowb = bm0 + wm + (i << 4) + (khi << 2);
#pragma unroll
      for (int r = 0; r < 4; ++r)
        op[(size_t)(rowb + r) * 1024 + col] = f2bf(acc[i][j][r]);
    }
}

// ------- fused stage-2 + combine: one block per (b,h) -> stt[bh][e][d] -------
__global__ __launch_bounds__(256)
void sc_k(const short* __restrict__ wt, const short* __restrict__ Tt,
          const float* __restrict__ u, const float* __restrict__ w,
          const float* __restrict__ bk, const float* __restrict__ bv,
          short* __restrict__ stt) {
  __shared__ short Al[64 * 40];
  __shared__ short Bl[64 * 40];
  const int h = blockIdx.x & 15, b = blockIdx.x >> 4;
  const int tid = threadIdx.x, lane = tid & 63, wid = tid >> 6;
  const int srow = tid >> 2, sch = (tid & 3) << 3;
  const int cl = lane & 15, khi = lane >> 4;

  f32x4 acc2[2][4];
#pragma unroll
  for (int k = 0; k < 2; ++k)
#pragma unroll
    for (int j = 0; j < 4; ++j) acc2[k][j] = f32x4{0.f, 0.f, 0.f, 0.f};

#pragma unroll
  for (int k = 0; k < 2; ++k) {
    const short* Ap = wt + ((size_t)(1 + k) << 20) + ((size_t)(h * 64) << 10);
    const short* Bp = Tt + ((size_t)b << 21) + ((size_t)(k * 1024 + h * 64) << 10);
#pragma unroll 1
    for (int ns = 0; ns < 1024; ns += 32) {
      bf16x8 va = *(const bf16x8*)(Ap + ((size_t)srow << 10) + ns + sch);
      bf16x8 vb = *(const bf16x8*)(Bp + ((size_t)srow << 10) + ns + sch);
      __syncthreads();
      *(bf16x8*)(Al + srow * 40 + sch) = va;
      *(bf16x8*)(Bl + srow * 40 + sch) = vb;
      __syncthreads();
      bf16x8 a = *(const bf16x8*)(Al + (wid * 16 + cl) * 40 + (khi << 3));
#pragma unroll
      for (int j = 0; j < 4; ++j) {
        bf16x8 bb = *(const bf16x8*)(Bl + (j * 16 + cl) * 40 + (khi << 3));
        acc2[k][j] = __builtin_amdgcn_mfma_f32_16x16x32_bf16(a, bb, acc2[k][j], 0, 0, 0);
      }
    }
  }

  const int d0 = wid * 16 + (khi << 2);
  const float invN = 1.0f / 4096.0f;
#pragma unroll
  for (int j = 0; j < 4; ++j) {
    const int e = j * 16 + cl;
    s16x4 pk;
#pragma unroll
    for (int r = 0; r < 4; ++r) {
      const int d = d0 + r;
      float m[2];
#pragma unroll
      for (int k = 0; k < 2; ++k) {
        const float bkd = bk[k * 1024 + h * 64 + d];
        const float bve = bv[k * 1024 + h * 64 + e];
        const float ud = u[(k * 4 + b) * 1024 + h * 64 + d];
        const float we = w[(k * 4 + b) * 1024 + h * 64 + e];
        m[k] = acc2[k][j][r] + (ud * bve + bkd * we + 4096.f * bkd * bve) * invN;
      }
      pk[r] = f2bf(m[0] * m[1]);
    }
    *(s16x4*)(stt + ((size_t)(b * 16 + h) << 12) + (e << 6) + d0) = pk;
  }
}

// ---------------- out_att = q @ state per (b,h) -> bf16 + LN-stat atomics ----------------
__global__ __launch_bounds__(256)
void attn_k(const short* __restrict__ q, const short* __restrict__ stt,
            short* __restrict__ oat, float* __restrict__ musum,
            float* __restrict__ sqsum) {
  __shared__ short Al[128 * 72];
  __shared__ short Bl[64 * 72];
  const int tid = threadIdx.x;
  const int lane = tid & 63;
  const int wid = tid >> 6;
  const int mc = blockIdx.x;
  const int bh = blockIdx.y;
  const int b = bh >> 4, h = bh & 15;
  const size_t qbase = ((size_t)(b * 4096 + mc * 128)) * 1024 + h * 64;
#pragma unroll
  for (int s = 0; s < 4; ++s) {
    const int idx = tid + s * 256;
    const int row = idx >> 3, cc = (idx & 7) << 3;
    *(bf16x8*)(Al + row * 72 + cc) = *(const bf16x8*)(q + qbase + (size_t)row * 1024 + cc);
  }
#pragma unroll
  for (int s = 0; s < 2; ++s) {
    const int idx = tid + s * 256;
    const int row = idx >> 3, cc = (idx & 7) << 3;
    *(bf16x8*)(Bl + row * 72 + cc) = *(const bf16x8*)(stt + (bh << 12) + (row << 6) + cc);
  }
  __syncthreads();
  f32x4 acc[2][4];
#pragma unroll
  for (int i = 0; i < 2; ++i)
#pragma unroll
    for (int j = 0; j < 4; ++j) acc[i][j] = f32x4{0.f, 0.f, 0.f, 0.f};
#pragma unroll
  for (int ks = 0; ks < 2; ++ks) {
    bf16x8 a0 = *(const bf16x8*)(Al + (wid * 32 + (lane & 15)) * 72 + ks * 32 + ((lane >> 4) << 3));
    bf16x8 a1 = *(const bf16x8*)(Al + (wid * 32 + 16 + (lane & 15)) * 72 + ks * 32 + ((lane >> 4) << 3));
#pragma unroll
    for (int j = 0; j < 4; ++j) {
      bf16x8 bb = *(const bf16x8*)(Bl + (j * 16 + (lane & 15)) * 72 + ks * 32 + ((lane >> 4) << 3));
      acc[0][j] = __builtin_amdgcn_mfma_f32_16x16x32_bf16(a0, bb, acc[0][j], 0, 0, 0);
      acc[1][j] = __builtin_amdgcn_mfma_f32_16x16x32_bf16(a1, bb, acc[1][j], 0, 0, 0);
    }
  }
  const int r0 = wid * 32 + ((lane >> 4) << 2);
  const int cl = lane & 15;
#pragma unroll
  for (int i = 0; i < 2; ++i) {
    s16x4 pk[4];
#pragma unroll
    for (int j = 0; j < 4; ++j) {
#pragma unroll
      for (int r = 0; r < 4; ++r) pk[j][r] = f2bf(acc[i][j][r]);
#pragma unroll
      for (int r = 0; r < 4; ++r) {
        const int row = b * 4096 + mc * 128 + r0 + i * 16 + r;
        oat[(size_t)row * 1024 + h * 64 + j * 16 + cl] = pk[j][r];
      }
    }
#pragma unroll
    for (int r = 0; r < 4; ++r) {
      float sv = 0.f, sq = 0.f;
#pragma unroll
      for (int j = 0; j < 4; ++j) {
        const float fv = bf2f(pk[j][r]);
        sv += fv; sq += fv * fv;
      }
#pragma unroll
      for (int m = 1; m < 16; m <<= 1) {
        sv += __shfl_xor(sv, m);
        sq += __shfl_xor(sq, m);
      }
      if (cl == 0) {
        const int row = b * 4096 + mc * 128 + r0 + i * 16 + r;
        atomicAdd(&musum[row], sv);
        atomicAdd(&sqsum[row], sq);
      }
    }
  }
}

// ---------------- final GEMM with folded LayerNorm (mu/rstd from atomic sums) ----------------
__global__ __launch_bounds__(512, 2)
void gemmo_k(const short* __restrict__ A, const short* __restrict__ WT,
             const float* __restrict__ musum, const float* __restrict__ sqsum,
             const float* __restrict__ uu, const float* __restrict__ tt,
             float* __restrict__ fout) {
  extern __shared__ short lds[];
  const int tid = threadIdx.x;
  const int lane = tid & 63;
  const int wv = tid >> 6;
  const int wm = wv >> 2;
  const int wn = wv & 3;
  const int swz = ((blockIdx.x & 7) << 5) + (blockIdx.x >> 3);
  const int bm0 = (swz >> 2) << 8;   // bn-inner: A-slab L2 reuse
  const int bn0 = (swz & 3) << 8;

  const int lrow = ((lane >> 3) << 1) | ((lane >> 2) & 1);
  const int kc = ((lane & 3) ^ ((lane >> 3) & 3)) << 3;
  const int cl = lane & 15;
  const int khi = lane >> 4;

  f32x4 acc[8][4];
#pragma unroll
  for (int i = 0; i < 8; ++i)
#pragma unroll
    for (int j = 0; j < 4; ++j) acc[i][j] = f32x4{0.f, 0.f, 0.f, 0.f};

  auto stage = [&](int buf, int t) {
    const int k0 = (t << 5) + kc;
    short* ab = lds + (buf << 14);
    short* bb = ab + 8192;
#pragma unroll
    for (int c = 0; c < 2; ++c) {
      const int un = wv * 2 + c;
      GLD_LDS(A + (size_t)(bm0 + (un << 4) + lrow) * 1024 + k0, ab + (un << 9));
      GLD_LDS(WT + (size_t)(bn0 + (un << 4) + lrow) * 1024 + k0, bb + (un << 9));
    }
  };

  auto compute = [&](int buf) {
    const short* ab = lds + (buf << 14);
    const short* bb = ab + 8192;
    bf16x8 af[8], bfr[4];
#pragma unroll
    for (int i = 0; i < 8; ++i) {
      const int R = (wm << 7) + (i << 4) + cl;
      af[i] = *(const bf16x8*)(ab + (R << 5) + ((khi ^ ((R >> 1) & 3)) << 3));
    }
#pragma unroll
    for (int j = 0; j < 4; ++j) {
      const int C = (wn << 6) + (j << 4) + cl;
      bfr[j] = *(const bf16x8*)(bb + (C << 5) + ((khi ^ ((C >> 1) & 3)) << 3));
    }
#pragma unroll
    for (int i = 0; i < 8; ++i)
#pragma unroll
      for (int j = 0; j < 4; ++j)
        acc[i][j] = __builtin_amdgcn_mfma_f32_16x16x32_bf16(af[i], bfr[j], acc[i][j], 0, 0, 0);
  };

  stage(0, 0);
  stage(1, 1);
  asm volatile("s_waitcnt vmcnt(4)" ::: "memory");
  __builtin_amdgcn_s_barrier();
#pragma unroll 1
  for (int t = 0; t < 30; ++t) {
    stage((t + 2) & 3, t + 2);
    compute(t & 3);
    asm volatile("s_waitcnt vmcnt(4)" ::: "memory");
    __builtin_amdgcn_s_barrier();
  }
  compute(2);
  asm volatile("s_waitcnt vmcnt(0)" ::: "memory");
  __builtin_amdgcn_s_barrier();
  compute(3);

#pragma unroll
  for (int i = 0; i < 8; ++i) {
    const int rowb = bm0 + (wm << 7) + (i << 4) + (khi << 2);
    const float4 ms = *(const float4*)(musum + rowb);
    const float4 qs = *(const float4*)(sqsum + rowb);
    float mu[4], rs[4];
    mu[0] = ms.x * (1.0f / 1024.0f); mu[1] = ms.y * (1.0f / 1024.0f);
    mu[2] = ms.z * (1.0f / 1024.0f); mu[3] = ms.w * (1.0f / 1024.0f);
    rs[0] = rsqrtf(fmaxf(qs.x * (1.0f / 1024.0f) - mu[0] * mu[0], 0.f) + 1e-5f);
    rs[1] = rsqrtf(fmaxf(qs.y * (1.0f / 1024.0f) - mu[1] * mu[1], 0.f) + 1e-5f);
    rs[2] = rsqrtf(fmaxf(qs.z * (1.0f / 1024.0f) - mu[2] * mu[2], 0.f) + 1e-5f);
    rs[3] = rsqrtf(fmaxf(qs.w * (1.0f / 1024.0f) - mu[3] * mu[3], 0.f) + 1e-5f);
#pragma unroll
    for (int j = 0; j < 4; ++j) {
      const int col = bn0 + (wn << 6) + (j << 4) + cl;
      const float uc = uu[col];
      const float tc = tt[col];
#pragma unroll
      for (int r = 0; r < 4; ++r)
        fout[(size_t)(rowb + r) * 1024 + col] = rs[r] * (acc[i][j][r] - mu[r] * uc) + tc;
    }
  }
}

extern "C" void kernel_launch(void* const* d_in, const int* in_sizes, int n_in,
                              void* d_out, int out_size, void* d_ws, size_t ws_size,
                              hipStream_t stream) {
  const float* x = (const float*)d_in[0];
  const float* Wq = (const float*)d_in[1];
  const float* bq = (const float*)d_in[2];
  const float* Wk = (const float*)d_in[3];
  const float* bk = (const float*)d_in[4];
  const float* Wv = (const float*)d_in[5];
  const float* bv = (const float*)d_in[6];
  const float* Wo = (const float*)d_in[7];
  const float* bo = (const float*)d_in[8];
  const float* lng = (const float*)d_in[9];
  const float* lnb = (const float*)d_in[10];

  char* ws = (char*)d_ws;
  // ---- verified non-overlapping layout ----
  short* xb = (short*)(ws + 0);             // [0, 33554432)
  short* wt = (short*)(ws + 33554432);      // [33554432, 46137344)
  short* q = (short*)(ws + 46137344);       // [46137344, 79691776)
  short* xbT = (short*)(ws + 79691776);     // [79691776, 113246208) dead after gram -> oat
  short* Gt = (short*)(ws + 113246208);     // [113246208, 121634816)
  short* Tt = (short*)(ws + 121634816);     // [121634816, 138412032)
  short* stt = (short*)(ws + 138412032);    // [138412032, 138936320)
  float* u = (float*)(ws + 138936320);      // [138936320, 138969088)
  float* w = (float*)(ws + 138969088);      // [138969088, 139001856)
  float* uu = (float*)(ws + 139001856);     // [139001856, 139005952)
  float* tt = (float*)(ws + 139005952);     // [139005952, 139010048)
  float* s = (float*)(ws + 139010048);      // [139010048, 139026432)  zeroed
  float* musum = (float*)(ws + 139026432);  // [139026432, 139091968)  zeroed
  float* sqsum = (float*)(ws + 139091968);  // [139091968, 139157504)  zeroed
  float* Pg = (float*)(ws + 143351808);     // [143351808, 206266368) 240 x 256KB chunks
  short* oat = xbT;

  hipMemsetAsync(s, 0, 147456, stream);  // s + musum + sqsum contiguous 144KB
  convt_k<<<dim3(16, 64, 4), 256, 0, stream>>>(x, xb, xbT, s);
  twc_k<<<dim3(32, 32, 6), dim3(32, 8), 0, stream>>>(Wq, Wk, Wv, Wo, lng, wt);
  gemv_k<<<dim3(16, 4, 4), 256, 0, stream>>>(wt, s, u, w);
  ut_k<<<16, 256, 0, stream>>>(Wo, lng, lnb, bo, uu, tt);

  // fused: triangle-gram split-K partials (even ids) + q projection (odd ids)
  gramq_k<<<496, 512, 131072, stream>>>(xb, xbT, wt, bq, q, Pg);
  gred6_k<<<640, 256, 0, stream>>>(Pg, Gt);
  gemm128_k<<<dim3(128, 4), 256, 65536, stream>>>(wt + 3145728, Gt, Tt);
  sc_k<<<64, 256, 0, stream>>>(wt, Tt, u, w, bk, bv, stt);

  attn_k<<<dim3(32, 64), 256, 0, stream>>>(q, stt, oat, musum, sqsum);
  gemmo_k<<<256, 512, 131072, stream>>>(oat, wt + 5242880, musum, sqsum, uu, tt,
                                        (float*)d_out);
}